// Round 1
// baseline (2551.246 us; speedup 1.0000x reference)
//
#include <hip/hip_runtime.h>
#include <cstdint>
#include <cstddef>

typedef float f4 __attribute__((ext_vector_type(4)));

#define LN_EPS 1e-5f

// ------------------------------------------------------------------
// elementwise add: out = a + b   (n4 = element count / 4)
// ------------------------------------------------------------------
__global__ __launch_bounds__(256) void add_kernel(const float* __restrict__ a,
                                                  const float* __restrict__ b,
                                                  float* __restrict__ out, int n4) {
  int i = blockIdx.x * blockDim.x + threadIdx.x;
  if (i < n4) {
    f4 x = ((const f4*)a)[i];
    f4 y = ((const f4*)b)[i];
    ((f4*)out)[i] = x + y;
  }
}

// ------------------------------------------------------------------
// GEMM: C[M,N] = A[M,K] @ W[N,K]^T + bias[N]  (optional relu)
// A, W row-major with K contiguous. M%64==0, N%64==0, K%32==0.
// 64x64 tile, BK=32, 256 threads, 4x4 microtile/thread.
// LDS stored transposed [BK][BM+4] so compute reads are float4.
// ------------------------------------------------------------------
#define BM 64
#define BN 64
#define BK 32
__global__ __launch_bounds__(256) void gemm_kernel(
    const float* __restrict__ A, const float* __restrict__ W,
    const float* __restrict__ bias, float* __restrict__ C,
    int M, int N, int K, int relu) {
  __shared__ float As[BK][BM + 4];
  __shared__ float Ws[BK][BN + 4];
  const int tid = threadIdx.x;
  const int bm = blockIdx.x * BM;
  const int bn = blockIdx.y * BN;
  const int ty = tid >> 4, tx = tid & 15;
  const int i0 = ty * 4, j0 = tx * 4;
  const int lrow = tid >> 3;        // 0..31
  const int lc4 = (tid & 7) * 4;    // 0,4,...,28

  float acc[4][4] = {};

  for (int k0 = 0; k0 < K; k0 += BK) {
    __syncthreads();
    {
      f4 v0 = *(const f4*)(A + (size_t)(bm + lrow) * K + k0 + lc4);
      f4 v1 = *(const f4*)(A + (size_t)(bm + 32 + lrow) * K + k0 + lc4);
#pragma unroll
      for (int c = 0; c < 4; ++c) {
        As[lc4 + c][lrow] = v0[c];
        As[lc4 + c][32 + lrow] = v1[c];
      }
      f4 w0 = *(const f4*)(W + (size_t)(bn + lrow) * K + k0 + lc4);
      f4 w1 = *(const f4*)(W + (size_t)(bn + 32 + lrow) * K + k0 + lc4);
#pragma unroll
      for (int c = 0; c < 4; ++c) {
        Ws[lc4 + c][lrow] = w0[c];
        Ws[lc4 + c][32 + lrow] = w1[c];
      }
    }
    __syncthreads();
#pragma unroll
    for (int k = 0; k < BK; ++k) {
      f4 a = *(const f4*)&As[k][i0];
      f4 w = *(const f4*)&Ws[k][j0];
#pragma unroll
      for (int ii = 0; ii < 4; ++ii)
#pragma unroll
        for (int jj = 0; jj < 4; ++jj)
          acc[ii][jj] = fmaf(a[ii], w[jj], acc[ii][jj]);
    }
  }

#pragma unroll
  for (int ii = 0; ii < 4; ++ii) {
    int row = bm + i0 + ii;
    f4 v;
#pragma unroll
    for (int jj = 0; jj < 4; ++jj) {
      float t = acc[ii][jj] + bias[bn + j0 + jj];
      if (relu) t = fmaxf(t, 0.f);
      v[jj] = t;
    }
    *(f4*)(C + (size_t)row * N + bn + j0) = v;
  }
}

// ------------------------------------------------------------------
// Attention: O[l,b,h*32+d] = softmax_s(Q.K^T*scale + bias) @ V
// Q: (L,B,256), K/V: (S,B,256), head slice h*32..h*32+31.
// bias (optional): (B,L,S) added to logits (same for all h).
// 1 thread = 1 query row; K/V chunks of 64 rows staged in LDS;
// online softmax with rescale-on-new-max.
// grid: (B*H, ceil(L/256)), block 256.
// ------------------------------------------------------------------
template <int HAS_BIAS>
__global__ __launch_bounds__(256) void attn_kernel(
    const float* __restrict__ Q, const float* __restrict__ Kp,
    const float* __restrict__ Vp, float* __restrict__ O,
    const float* __restrict__ bias, int B, int H, int L, int S, float scale) {
  constexpr int HD = 32, CH = 64;
  __shared__ float Ks[CH][HD + 4];
  __shared__ float Vs[CH][HD + 4];
  const int tid = threadIdx.x;
  const int b = blockIdx.x / H, h = blockIdx.x % H;
  const int l = blockIdx.y * 256 + tid;
  const bool active = (l < L);
  const int lq = active ? l : (L - 1);

  float q[HD];
  {
    const float* qp = Q + ((size_t)lq * B + b) * 256 + h * HD;
#pragma unroll
    for (int d = 0; d < HD; d += 4) {
      f4 t = *(const f4*)(qp + d);
      q[d] = t[0]; q[d + 1] = t[1]; q[d + 2] = t[2]; q[d + 3] = t[3];
    }
  }
  const float* brow = nullptr;
  if (HAS_BIAS) brow = bias + ((size_t)b * L + lq) * S;

  float m = -1e30f, lsum = 0.f;
  float o[HD] = {};

  for (int s0 = 0; s0 < S; s0 += CH) {
    const int cnt = min(CH, S - s0);
    __syncthreads();
#pragma unroll
    for (int i = 0; i < 2; ++i) {
      int f4i = i * 256 + tid;
      int row = f4i >> 3;
      int c = (f4i & 7) * 4;
      if (s0 + row < S) {
        size_t srcoff = ((size_t)(s0 + row) * B + b) * 256 + h * HD + c;
        *(f4*)&Ks[row][c] = *(const f4*)(Kp + srcoff);
        *(f4*)&Vs[row][c] = *(const f4*)(Vp + srcoff);
      }
    }
    __syncthreads();

    for (int j = 0; j < cnt; ++j) {
      float dot = 0.f;
#pragma unroll
      for (int d = 0; d < HD; d += 4) {
        f4 kk = *(const f4*)&Ks[j][d];
        dot = fmaf(q[d], kk[0], dot);
        dot = fmaf(q[d + 1], kk[1], dot);
        dot = fmaf(q[d + 2], kk[2], dot);
        dot = fmaf(q[d + 3], kk[3], dot);
      }
      float logit = dot * scale;
      if (HAS_BIAS) logit += brow[s0 + j];
      if (logit > m) {
        float r = __expf(m - logit);   // new max: p = 1
        lsum = lsum * r + 1.f;
#pragma unroll
        for (int d = 0; d < HD; d += 4) {
          f4 vv = *(const f4*)&Vs[j][d];
          o[d] = o[d] * r + vv[0];
          o[d + 1] = o[d + 1] * r + vv[1];
          o[d + 2] = o[d + 2] * r + vv[2];
          o[d + 3] = o[d + 3] * r + vv[3];
        }
        m = logit;
      } else {
        float p = __expf(logit - m);
        lsum += p;
#pragma unroll
        for (int d = 0; d < HD; d += 4) {
          f4 vv = *(const f4*)&Vs[j][d];
          o[d] = fmaf(p, vv[0], o[d]);
          o[d + 1] = fmaf(p, vv[1], o[d + 1]);
          o[d + 2] = fmaf(p, vv[2], o[d + 2]);
          o[d + 3] = fmaf(p, vv[3], o[d + 3]);
        }
      }
    }
  }

  if (active) {
    float inv = 1.f / lsum;
    float* op = O + ((size_t)l * B + b) * 256 + h * HD;
#pragma unroll
    for (int d = 0; d < HD; d += 4) {
      f4 t;
      t[0] = o[d] * inv; t[1] = o[d + 1] * inv;
      t[2] = o[d + 2] * inv; t[3] = o[d + 3] * inv;
      *(f4*)(op + d) = t;
    }
  }
}

// ------------------------------------------------------------------
// LayerNorm over last dim (256): out = LN(x + res)*g + b
// block = 256 (one row), grid = rows. res may be null.
// ------------------------------------------------------------------
__global__ __launch_bounds__(256) void ln_kernel(
    const float* __restrict__ x, const float* __restrict__ res,
    const float* __restrict__ g, const float* __restrict__ b,
    float* __restrict__ out) {
  const int row = blockIdx.x, tid = threadIdx.x;
  float v = x[(size_t)row * 256 + tid];
  if (res) v += res[(size_t)row * 256 + tid];
  float s = v, s2 = v * v;
#pragma unroll
  for (int off = 32; off >= 1; off >>= 1) {
    s += __shfl_down(s, off);
    s2 += __shfl_down(s2, off);
  }
  __shared__ float red[8];
  int wv = tid >> 6;
  if ((tid & 63) == 0) { red[wv] = s; red[4 + wv] = s2; }
  __syncthreads();
  if (tid == 0) {
    float ts = red[0] + red[1] + red[2] + red[3];
    float ts2 = red[4] + red[5] + red[6] + red[7];
    float mu = ts * (1.f / 256.f);
    float var = ts2 * (1.f / 256.f) - mu * mu;
    red[0] = mu;
    red[1] = rsqrtf(var + LN_EPS);
  }
  __syncthreads();
  out[(size_t)row * 256 + tid] = (v - red[0]) * red[1] * g[tid] + b[tid];
}

// ------------------------------------------------------------------
// Host orchestration
// ------------------------------------------------------------------
extern "C" void kernel_launch(void* const* d_in, const int* in_sizes, int n_in,
                              void* d_out, int out_size, void* d_ws, size_t ws_size,
                              hipStream_t stream) {
  const float* src         = (const float*)d_in[0];
  const float* pos         = (const float*)d_in[1];
  const float* query_embed = (const float*)d_in[2];
  const float* cam_mask    = (const float*)d_in[3];
  const float* enc_qkv_w   = (const float*)d_in[4];
  const float* enc_qkv_b   = (const float*)d_in[5];
  const float* enc_out_w   = (const float*)d_in[6];
  const float* enc_out_b   = (const float*)d_in[7];
  const float* enc_ln1_g   = (const float*)d_in[8];
  const float* enc_ln1_b   = (const float*)d_in[9];
  const float* enc_ff1_w   = (const float*)d_in[10];
  const float* enc_ff1_b   = (const float*)d_in[11];
  const float* enc_ff2_w   = (const float*)d_in[12];
  const float* enc_ff2_b   = (const float*)d_in[13];
  const float* enc_ln2_g   = (const float*)d_in[14];
  const float* enc_ln2_b   = (const float*)d_in[15];
  const float* dec_sa_qkv_w= (const float*)d_in[16];
  const float* dec_sa_qkv_b= (const float*)d_in[17];
  const float* dec_sa_out_w= (const float*)d_in[18];
  const float* dec_sa_out_b= (const float*)d_in[19];
  const float* dec_ln1_g   = (const float*)d_in[20];
  const float* dec_ln1_b   = (const float*)d_in[21];
  const float* dec_ca_qkv_w= (const float*)d_in[22];
  const float* dec_ca_qkv_b= (const float*)d_in[23];
  const float* dec_ca_out_w= (const float*)d_in[24];
  const float* dec_ca_out_b= (const float*)d_in[25];
  const float* dec_ln2_g   = (const float*)d_in[26];
  const float* dec_ln2_b   = (const float*)d_in[27];
  const float* dec_ff1_w   = (const float*)d_in[28];
  const float* dec_ff1_b   = (const float*)d_in[29];
  const float* dec_ff2_w   = (const float*)d_in[30];
  const float* dec_ff2_b   = (const float*)d_in[31];
  const float* dec_ln3_g   = (const float*)d_in[32];
  const float* dec_ln3_b   = (const float*)d_in[33];
  const float* dec_norm_g  = (const float*)d_in[34];
  const float* dec_norm_b  = (const float*)d_in[35];

  float* ws = (float*)d_ws;
  // workspace layout (floats)
  float* mem  = ws + 0;          //  8192*256
  float* qk   = ws + 2097152;    //  8192*256  (also proj scratch)
  float* qb   = ws + 4194304;    //  8192*256
  float* kb   = ws + 6291456;    //  8192*256
  float* vb   = ws + 8388608;    //  8192*256
  float* ao   = ws + 10485760;   //  8192*256
  float* ff   = ws + 12582912;   //  8192*2048
  float* tgt  = ws + 29360128;   //  640*256
  float* tqk  = ws + 29523968;   //  640*256
  float* tq   = ws + 29687808;   //  640*256
  float* tao  = ws + 29851648;   //  640*256
  float* tpr  = ws + 30015488;   //  640*256
  float* tff  = ws + 30179328;   //  640*2048

  const float scale = 0.17677669529663687f;  // 1/sqrt(32)

  // mem = src
  hipMemcpyAsync(mem, src, (size_t)2097152 * sizeof(float),
                 hipMemcpyDeviceToDevice, stream);

  // ---------------- encoder ----------------
  for (int i = 0; i < 2; ++i) {
    const float* qkvw = enc_qkv_w + (size_t)i * 768 * 256;
    const float* qkvb = enc_qkv_b + (size_t)i * 768;
    add_kernel<<<2048, 256, 0, stream>>>(mem, pos, qk, 524288);
    dim3 g1(128, 4);
    gemm_kernel<<<g1, 256, 0, stream>>>(qk, qkvw, qkvb, qb, 8192, 256, 256, 0);
    gemm_kernel<<<g1, 256, 0, stream>>>(qk, qkvw + 65536, qkvb + 256, kb, 8192, 256, 256, 0);
    gemm_kernel<<<g1, 256, 0, stream>>>(mem, qkvw + 131072, qkvb + 512, vb, 8192, 256, 256, 0);
    attn_kernel<0><<<dim3(64, 4), 256, 0, stream>>>(qb, kb, vb, ao, nullptr,
                                                    8, 8, 1024, 1024, scale);
    gemm_kernel<<<g1, 256, 0, stream>>>(ao, enc_out_w + (size_t)i * 65536,
                                        enc_out_b + i * 256, qk, 8192, 256, 256, 0);
    ln_kernel<<<8192, 256, 0, stream>>>(mem, qk, enc_ln1_g + i * 256,
                                        enc_ln1_b + i * 256, mem);
    gemm_kernel<<<dim3(128, 32), 256, 0, stream>>>(
        mem, enc_ff1_w + (size_t)i * 524288, enc_ff1_b + i * 2048, ff,
        8192, 2048, 256, 1);
    gemm_kernel<<<dim3(128, 4), 256, 0, stream>>>(
        ff, enc_ff2_w + (size_t)i * 524288, enc_ff2_b + i * 256, qk,
        8192, 256, 2048, 0);
    ln_kernel<<<8192, 256, 0, stream>>>(mem, qk, enc_ln2_g + i * 256,
                                        enc_ln2_b + i * 256, mem);
  }

  // ---------------- decoder ----------------
  hipMemsetAsync(tgt, 0, (size_t)163840 * sizeof(float), stream);
  // qk = mem + pos (K input of cross-attention, constant over dec layers)
  add_kernel<<<2048, 256, 0, stream>>>(mem, pos, qk, 524288);

  for (int i = 0; i < 2; ++i) {
    const float* saw = dec_sa_qkv_w + (size_t)i * 768 * 256;
    const float* sab = dec_sa_qkv_b + (size_t)i * 768;
    const float* caw = dec_ca_qkv_w + (size_t)i * 768 * 256;
    const float* cab = dec_ca_qkv_b + (size_t)i * 768;
    dim3 gd(10, 4);
    // self-attention
    add_kernel<<<160, 256, 0, stream>>>(tgt, query_embed, tqk, 40960);
    gemm_kernel<<<gd, 256, 0, stream>>>(tqk, saw, sab, tq, 640, 256, 256, 0);
    gemm_kernel<<<gd, 256, 0, stream>>>(tqk, saw + 65536, sab + 256, kb, 640, 256, 256, 0);
    gemm_kernel<<<gd, 256, 0, stream>>>(tgt, saw + 131072, sab + 512, vb, 640, 256, 256, 0);
    attn_kernel<0><<<dim3(64, 1), 256, 0, stream>>>(tq, kb, vb, tao, nullptr,
                                                    8, 8, 80, 80, scale);
    gemm_kernel<<<gd, 256, 0, stream>>>(tao, dec_sa_out_w + (size_t)i * 65536,
                                        dec_sa_out_b + i * 256, tpr, 640, 256, 256, 0);
    ln_kernel<<<640, 256, 0, stream>>>(tgt, tpr, dec_ln1_g + i * 256,
                                       dec_ln1_b + i * 256, tgt);
    // cross-attention
    add_kernel<<<160, 256, 0, stream>>>(tgt, query_embed, tqk, 40960);
    gemm_kernel<<<gd, 256, 0, stream>>>(tqk, caw, cab, tq, 640, 256, 256, 0);
    gemm_kernel<<<dim3(128, 4), 256, 0, stream>>>(qk, caw + 65536, cab + 256, kb,
                                                  8192, 256, 256, 0);
    gemm_kernel<<<dim3(128, 4), 256, 0, stream>>>(mem, caw + 131072, cab + 512, vb,
                                                  8192, 256, 256, 0);
    attn_kernel<1><<<dim3(64, 1), 256, 0, stream>>>(tq, kb, vb, tao, cam_mask,
                                                    8, 8, 80, 1024, scale);
    gemm_kernel<<<gd, 256, 0, stream>>>(tao, dec_ca_out_w + (size_t)i * 65536,
                                        dec_ca_out_b + i * 256, tpr, 640, 256, 256, 0);
    ln_kernel<<<640, 256, 0, stream>>>(tgt, tpr, dec_ln2_g + i * 256,
                                       dec_ln2_b + i * 256, tgt);
    // feed-forward
    gemm_kernel<<<dim3(10, 32), 256, 0, stream>>>(
        tgt, dec_ff1_w + (size_t)i * 524288, dec_ff1_b + i * 2048, tff,
        640, 2048, 256, 1);
    gemm_kernel<<<dim3(10, 4), 256, 0, stream>>>(
        tff, dec_ff2_w + (size_t)i * 524288, dec_ff2_b + i * 256, tpr,
        640, 256, 2048, 0);
    ln_kernel<<<640, 256, 0, stream>>>(tgt, tpr, dec_ln3_g + i * 256,
                                       dec_ln3_b + i * 256, tgt);
  }

  // final norm -> output (fp32)
  ln_kernel<<<640, 256, 0, stream>>>(tgt, nullptr, dec_norm_g, dec_norm_b,
                                     (float*)d_out);
}

// Round 2
// 1468.594 us; speedup vs baseline: 1.7372x; 1.7372x over previous
//
#include <hip/hip_runtime.h>
#include <hip/hip_bf16.h>
#include <cstdint>
#include <cstddef>

typedef __hip_bfloat16 bf16;
typedef float f4 __attribute__((ext_vector_type(4)));
typedef float f32x4 __attribute__((ext_vector_type(4)));
typedef short s8 __attribute__((ext_vector_type(8)));
typedef unsigned short u16x4 __attribute__((ext_vector_type(4)));

#define LN_EPS 1e-5f

// ------------------------------------------------------------------
// cast fp32 -> bf16
// ------------------------------------------------------------------
__global__ __launch_bounds__(256) void cast_kernel(const float* __restrict__ in,
                                                   bf16* __restrict__ out, int n4) {
  int i = blockIdx.x * 256 + threadIdx.x;
  if (i < n4) {
    f4 v = ((const f4*)in)[i];
    u16x4 o;
#pragma unroll
    for (int j = 0; j < 4; ++j) {
      bf16 h = __float2bfloat16(v[j]);
      o[j] = *reinterpret_cast<unsigned short*>(&h);
    }
    ((u16x4*)out)[i] = o;
  }
}

// ------------------------------------------------------------------
// add fp32 + fp32 -> bf16
// ------------------------------------------------------------------
__global__ __launch_bounds__(256) void add_bf16_kernel(const float* __restrict__ a,
                                                       const float* __restrict__ b,
                                                       bf16* __restrict__ out, int n4) {
  int i = blockIdx.x * 256 + threadIdx.x;
  if (i < n4) {
    f4 x = ((const f4*)a)[i];
    f4 y = ((const f4*)b)[i];
    u16x4 o;
#pragma unroll
    for (int j = 0; j < 4; ++j) {
      bf16 h = __float2bfloat16(x[j] + y[j]);
      o[j] = *reinterpret_cast<unsigned short*>(&h);
    }
    ((u16x4*)out)[i] = o;
  }
}

// ------------------------------------------------------------------
// MFMA GEMM: C[M,N] = A[M,K] @ W[N,K]^T + bias[N]
// A, W bf16 row-major (K contiguous). M%128==0, N%128==0, K%64==0.
// 128x128 tile, BK=64, 256 threads (4 waves, 2x2), 16x16x32 MFMA.
// LDS rows padded to 72 bf16 (144B) -> ~conflict-free b128 reads.
// ------------------------------------------------------------------
template <int RELU, int OUTBF16>
__global__ __launch_bounds__(256, 2) void mfma_gemm(
    const bf16* __restrict__ A, const bf16* __restrict__ W,
    const float* __restrict__ bias, float* __restrict__ C,
    bf16* __restrict__ Cb, int M, int N, int K) {
  __shared__ unsigned short As[128][72];
  __shared__ unsigned short Ws[128][72];
  const int tid = threadIdx.x;
  const int lane = tid & 63, wave = tid >> 6;
  const int wr = wave >> 1, wc = wave & 1;
  const int bm = blockIdx.x * 128, bn = blockIdx.y * 128;
  const int srow = tid >> 3, scol = (tid & 7) * 8;
  const int fr = lane & 15, fk = (lane >> 4) * 8;

  f32x4 acc[4][4] = {};

  for (int k0 = 0; k0 < K; k0 += 64) {
    __syncthreads();
#pragma unroll
    for (int i = 0; i < 4; ++i) {
      int r = srow + 32 * i;
      *(s8*)&As[r][scol] = *(const s8*)(A + (size_t)(bm + r) * K + k0 + scol);
      *(s8*)&Ws[r][scol] = *(const s8*)(W + (size_t)(bn + r) * K + k0 + scol);
    }
    __syncthreads();
#pragma unroll
    for (int ks = 0; ks < 2; ++ks) {
      int kc = ks * 32 + fk;
      s8 a[4], b[4];
#pragma unroll
      for (int mi = 0; mi < 4; ++mi)
        a[mi] = *(const s8*)&As[wr * 64 + mi * 16 + fr][kc];
#pragma unroll
      for (int ni = 0; ni < 4; ++ni)
        b[ni] = *(const s8*)&Ws[wc * 64 + ni * 16 + fr][kc];
#pragma unroll
      for (int mi = 0; mi < 4; ++mi)
#pragma unroll
        for (int ni = 0; ni < 4; ++ni)
          acc[mi][ni] = __builtin_amdgcn_mfma_f32_16x16x32_bf16(
              a[mi], b[ni], acc[mi][ni], 0, 0, 0);
    }
  }

  const int r0 = (lane >> 4) * 4;
#pragma unroll
  for (int mi = 0; mi < 4; ++mi) {
#pragma unroll
    for (int ni = 0; ni < 4; ++ni) {
      int col = bn + wc * 64 + ni * 16 + fr;
      float bv = bias[col];
#pragma unroll
      for (int r = 0; r < 4; ++r) {
        int row = bm + wr * 64 + mi * 16 + r0 + r;
        float t = acc[mi][ni][r] + bv;
        if (RELU) t = fmaxf(t, 0.f);
        if (OUTBF16)
          Cb[(size_t)row * N + col] = __float2bfloat16(t);
        else
          C[(size_t)row * N + col] = t;
      }
    }
  }
}

// ------------------------------------------------------------------
// Attention partial (flash-decoding S-split).
// Q:(L,B,256) K/V:(S,B,256) fp32, head slice h*32. bias:(B,L,S) optional.
// grid (B*H, nQchunk, nSchunk), block 256, 1 thread = 1 query row.
// Writes PO[c][bh][l][32], PM/PL[c][bh][l].
// ------------------------------------------------------------------
template <int HAS_BIAS>
__global__ __launch_bounds__(256) void attn_part(
    const float* __restrict__ Q, const float* __restrict__ Kp,
    const float* __restrict__ Vp, const float* __restrict__ bias,
    float* __restrict__ PO, float* __restrict__ PM, float* __restrict__ PL,
    int B, int H, int L, int S, int SC, float scale) {
  constexpr int HD = 32, CH = 64;
  __shared__ float Ks[CH][HD + 4];
  __shared__ float Vs[CH][HD + 4];
  const int tid = threadIdx.x;
  const int bh = blockIdx.x;
  const int b = bh / 8, h = bh & 7;  // H == 8
  const int l = blockIdx.y * 256 + tid;
  const bool active = (l < L);
  const int lq = active ? l : (L - 1);
  const int c = blockIdx.z;
  const int sb = c * SC;
  const int se = min(S, sb + SC);

  float q[HD];
  {
    const float* qp = Q + ((size_t)lq * B + b) * 256 + h * HD;
#pragma unroll
    for (int d = 0; d < HD; d += 4) {
      f4 t = *(const f4*)(qp + d);
      q[d] = t[0]; q[d + 1] = t[1]; q[d + 2] = t[2]; q[d + 3] = t[3];
    }
  }
  const float* brow = HAS_BIAS ? bias + ((size_t)b * L + lq) * S : nullptr;

  float m = -1e30f, lsum = 0.f;
  float o[HD] = {};

  for (int s0 = sb; s0 < se; s0 += CH) {
    const int cnt = min(CH, se - s0);
    __syncthreads();
#pragma unroll
    for (int i = 0; i < 2; ++i) {
      int fi = i * 256 + tid;
      int row = fi >> 3;
      int cc = (fi & 7) * 4;
      if (s0 + row < se) {
        size_t so = ((size_t)(s0 + row) * B + b) * 256 + h * HD + cc;
        *(f4*)&Ks[row][cc] = *(const f4*)(Kp + so);
        *(f4*)&Vs[row][cc] = *(const f4*)(Vp + so);
      }
    }
    __syncthreads();

    for (int j = 0; j < cnt; ++j) {
      float dot = 0.f;
#pragma unroll
      for (int d = 0; d < HD; d += 4) {
        f4 kk = *(const f4*)&Ks[j][d];
        dot = fmaf(q[d], kk[0], dot);
        dot = fmaf(q[d + 1], kk[1], dot);
        dot = fmaf(q[d + 2], kk[2], dot);
        dot = fmaf(q[d + 3], kk[3], dot);
      }
      float logit = dot * scale;
      if (HAS_BIAS) logit += brow[s0 + j];
      if (logit > m) {
        float r = __expf(m - logit);
        lsum = lsum * r + 1.f;
#pragma unroll
        for (int d = 0; d < HD; d += 4) {
          f4 vv = *(const f4*)&Vs[j][d];
          o[d] = o[d] * r + vv[0];
          o[d + 1] = o[d + 1] * r + vv[1];
          o[d + 2] = o[d + 2] * r + vv[2];
          o[d + 3] = o[d + 3] * r + vv[3];
        }
        m = logit;
      } else {
        float p = __expf(logit - m);
        lsum += p;
#pragma unroll
        for (int d = 0; d < HD; d += 4) {
          f4 vv = *(const f4*)&Vs[j][d];
          o[d] = fmaf(p, vv[0], o[d]);
          o[d + 1] = fmaf(p, vv[1], o[d + 1]);
          o[d + 2] = fmaf(p, vv[2], o[d + 2]);
          o[d + 3] = fmaf(p, vv[3], o[d + 3]);
        }
      }
    }
  }

  if (active) {
    size_t pi = ((size_t)c * gridDim.x + bh) * L + l;
    PM[pi] = m;
    PL[pi] = lsum;
    float* po = PO + pi * 32;
#pragma unroll
    for (int d = 0; d < HD; d += 4) {
      f4 t;
      t[0] = o[d]; t[1] = o[d + 1]; t[2] = o[d + 2]; t[3] = o[d + 3];
      *(f4*)(po + d) = t;
    }
  }
}

// ------------------------------------------------------------------
// Combine NC partials -> O bf16 (L,B,256)
// ------------------------------------------------------------------
__global__ __launch_bounds__(256) void attn_combine(
    const float* __restrict__ PO, const float* __restrict__ PM,
    const float* __restrict__ PL, bf16* __restrict__ O,
    int B, int H, int L, int NC) {
  int gid = blockIdx.x * 256 + threadIdx.x;
  int BH = B * H;
  if (gid >= BH * L) return;
  int bh = gid / L, l = gid - bh * L;
  int b = bh / 8, h = bh & 7;
  float M = -1e30f;
  for (int c = 0; c < NC; ++c) M = fmaxf(M, PM[((size_t)c * BH + bh) * L + l]);
  float lsum = 0.f;
  float o[32] = {};
  for (int c = 0; c < NC; ++c) {
    size_t pi = ((size_t)c * BH + bh) * L + l;
    float w = __expf(PM[pi] - M);
    lsum += PL[pi] * w;
    const f4* po = (const f4*)(PO + pi * 32);
#pragma unroll
    for (int d4 = 0; d4 < 8; ++d4) {
      f4 v = po[d4];
      o[d4 * 4] += w * v[0];
      o[d4 * 4 + 1] += w * v[1];
      o[d4 * 4 + 2] += w * v[2];
      o[d4 * 4 + 3] += w * v[3];
    }
  }
  float inv = 1.f / lsum;
  bf16* op = O + ((size_t)l * B + b) * 256 + h * 32;
#pragma unroll
  for (int d = 0; d < 32; ++d) op[d] = __float2bfloat16(o[d] * inv);
}

// ------------------------------------------------------------------
// LayerNorm over last dim (256): out = LN(x + res)*g + b ; dual output
// ------------------------------------------------------------------
__global__ __launch_bounds__(256) void ln_kernel(
    const float* __restrict__ x, const float* __restrict__ res,
    const float* __restrict__ g, const float* __restrict__ b,
    float* __restrict__ out, bf16* __restrict__ outb) {
  const int row = blockIdx.x, tid = threadIdx.x;
  size_t idx = (size_t)row * 256 + tid;
  float v = x[idx];
  if (res) v += res[idx];
  float s = v, s2 = v * v;
#pragma unroll
  for (int off = 32; off >= 1; off >>= 1) {
    s += __shfl_down(s, off);
    s2 += __shfl_down(s2, off);
  }
  __shared__ float red[8];
  int wv = tid >> 6;
  if ((tid & 63) == 0) { red[wv] = s; red[4 + wv] = s2; }
  __syncthreads();
  if (tid == 0) {
    float ts = red[0] + red[1] + red[2] + red[3];
    float ts2 = red[4] + red[5] + red[6] + red[7];
    float mu = ts * (1.f / 256.f);
    float var = ts2 * (1.f / 256.f) - mu * mu;
    red[0] = mu;
    red[1] = rsqrtf(var + LN_EPS);
  }
  __syncthreads();
  float y = (v - red[0]) * red[1] * g[tid] + b[tid];
  if (out) out[idx] = y;
  if (outb) outb[idx] = __float2bfloat16(y);
}

// ------------------------------------------------------------------
// Host orchestration
// ------------------------------------------------------------------
extern "C" void kernel_launch(void* const* d_in, const int* in_sizes, int n_in,
                              void* d_out, int out_size, void* d_ws, size_t ws_size,
                              hipStream_t stream) {
  const float* src         = (const float*)d_in[0];
  const float* pos         = (const float*)d_in[1];
  const float* query_embed = (const float*)d_in[2];
  const float* cam_mask    = (const float*)d_in[3];
  const float* enc_qkv_w   = (const float*)d_in[4];
  const float* enc_qkv_b   = (const float*)d_in[5];
  const float* enc_out_w   = (const float*)d_in[6];
  const float* enc_out_b   = (const float*)d_in[7];
  const float* enc_ln1_g   = (const float*)d_in[8];
  const float* enc_ln1_b   = (const float*)d_in[9];
  const float* enc_ff1_w   = (const float*)d_in[10];
  const float* enc_ff1_b   = (const float*)d_in[11];
  const float* enc_ff2_w   = (const float*)d_in[12];
  const float* enc_ff2_b   = (const float*)d_in[13];
  const float* enc_ln2_g   = (const float*)d_in[14];
  const float* enc_ln2_b   = (const float*)d_in[15];
  const float* dec_sa_qkv_w= (const float*)d_in[16];
  const float* dec_sa_qkv_b= (const float*)d_in[17];
  const float* dec_sa_out_w= (const float*)d_in[18];
  const float* dec_sa_out_b= (const float*)d_in[19];
  const float* dec_ln1_g   = (const float*)d_in[20];
  const float* dec_ln1_b   = (const float*)d_in[21];
  const float* dec_ca_qkv_w= (const float*)d_in[22];
  const float* dec_ca_qkv_b= (const float*)d_in[23];
  const float* dec_ca_out_w= (const float*)d_in[24];
  const float* dec_ca_out_b= (const float*)d_in[25];
  const float* dec_ln2_g   = (const float*)d_in[26];
  const float* dec_ln2_b   = (const float*)d_in[27];
  const float* dec_ff1_w   = (const float*)d_in[28];
  const float* dec_ff1_b   = (const float*)d_in[29];
  const float* dec_ff2_w   = (const float*)d_in[30];
  const float* dec_ff2_b   = (const float*)d_in[31];
  const float* dec_ln3_g   = (const float*)d_in[32];
  const float* dec_ln3_b   = (const float*)d_in[33];
  const float* dec_norm_g  = (const float*)d_in[34];
  const float* dec_norm_b  = (const float*)d_in[35];

  // ---------------- workspace layout ----------------
  size_t off = 0;
  char* base = (char*)d_ws;
  auto af = [&](size_t n) { float* p = (float*)(base + off); off += n * 4; return p; };
  auto ab = [&](size_t n) { bf16*  p = (bf16*)(base + off);  off += n * 2; return p; };

  float* mem  = af(2097152);
  float* r1   = af(2097152);
  float* qb   = af(2097152);
  float* kb   = af(2097152);
  float* vb   = af(2097152);
  float* pm   = af(262144);
  float* pl   = af(262144);
  float* tgt  = af(163840);
  float* tpr  = af(163840);
  bf16* memb  = ab(2097152);
  bf16* qkb   = ab(2097152);
  bf16* aob   = ab(2097152);
  bf16* ffb   = ab(16777216);           // FF scratch; aliased as PO (f32) during attn
  bf16* tgtb  = ab(163840);
  bf16* tqkb  = ab(163840);
  bf16* taob  = ab(163840);
  bf16* tffb  = ab(1310720);
  bf16* w_enc_qkv = ab(393216);
  bf16* w_enc_out = ab(131072);
  bf16* w_enc_ff1 = ab(1048576);
  bf16* w_enc_ff2 = ab(1048576);
  bf16* w_sa_qkv  = ab(393216);
  bf16* w_sa_out  = ab(131072);
  bf16* w_ca_qkv  = ab(393216);
  bf16* w_ca_out  = ab(131072);
  bf16* w_dec_ff1 = ab(1048576);
  bf16* w_dec_ff2 = ab(1048576);
  float* PO = (float*)ffb;              // 8.4M f32 capacity, enough for 4*64*1024*32

  const float scale = 0.17677669529663687f;  // 1/sqrt(32)

  auto cast = [&](const float* in, bf16* out, int n) {
    int n4 = n / 4;
    cast_kernel<<<(n4 + 255) / 256, 256, 0, stream>>>(in, out, n4);
  };
  auto gemm_f = [&](const bf16* A, const bf16* W, const float* bias, float* C,
                    int M, int N, int K) {
    mfma_gemm<0, 0><<<dim3(M / 128, N / 128), 256, 0, stream>>>(
        A, W, bias, C, nullptr, M, N, K);
  };
  auto gemm_bf_relu = [&](const bf16* A, const bf16* W, const float* bias, bf16* Cb,
                          int M, int N, int K) {
    mfma_gemm<1, 1><<<dim3(M / 128, N / 128), 256, 0, stream>>>(
        A, W, bias, nullptr, Cb, M, N, K);
  };

  // weight casts (fp32 -> bf16)
  cast(enc_qkv_w, w_enc_qkv, 393216);
  cast(enc_out_w, w_enc_out, 131072);
  cast(enc_ff1_w, w_enc_ff1, 1048576);
  cast(enc_ff2_w, w_enc_ff2, 1048576);
  cast(dec_sa_qkv_w, w_sa_qkv, 393216);
  cast(dec_sa_out_w, w_sa_out, 131072);
  cast(dec_ca_qkv_w, w_ca_qkv, 393216);
  cast(dec_ca_out_w, w_ca_out, 131072);
  cast(dec_ff1_w, w_dec_ff1, 1048576);
  cast(dec_ff2_w, w_dec_ff2, 1048576);

  // mem = src (fp32 + bf16)
  hipMemcpyAsync(mem, src, (size_t)2097152 * 4, hipMemcpyDeviceToDevice, stream);
  cast(src, memb, 2097152);

  // ---------------- encoder ----------------
  for (int i = 0; i < 2; ++i) {
    const bf16* wq = w_enc_qkv + (size_t)i * 196608;
    const float* qkvb = enc_qkv_b + (size_t)i * 768;
    add_bf16_kernel<<<2048, 256, 0, stream>>>(mem, pos, qkb, 524288);
    gemm_f(qkb, wq,          qkvb,       qb, 8192, 256, 256);
    gemm_f(qkb, wq + 65536,  qkvb + 256, kb, 8192, 256, 256);
    gemm_f(memb, wq + 131072, qkvb + 512, vb, 8192, 256, 256);
    attn_part<0><<<dim3(64, 4, 4), 256, 0, stream>>>(
        qb, kb, vb, nullptr, PO, pm, pl, 8, 8, 1024, 1024, 256, scale);
    attn_combine<<<256, 256, 0, stream>>>(PO, pm, pl, aob, 8, 8, 1024, 4);
    gemm_f(aob, w_enc_out + (size_t)i * 65536, enc_out_b + i * 256, r1,
           8192, 256, 256);
    ln_kernel<<<8192, 256, 0, stream>>>(mem, r1, enc_ln1_g + i * 256,
                                        enc_ln1_b + i * 256, mem, memb);
    gemm_bf_relu(memb, w_enc_ff1 + (size_t)i * 524288, enc_ff1_b + i * 2048, ffb,
                 8192, 2048, 256);
    gemm_f(ffb, w_enc_ff2 + (size_t)i * 524288, enc_ff2_b + i * 256, r1,
           8192, 256, 2048);
    ln_kernel<<<8192, 256, 0, stream>>>(mem, r1, enc_ln2_g + i * 256,
                                        enc_ln2_b + i * 256, mem, memb);
  }

  // ---------------- decoder ----------------
  hipMemsetAsync(tgt, 0, (size_t)163840 * 4, stream);
  hipMemsetAsync(tgtb, 0, (size_t)163840 * 2, stream);
  add_bf16_kernel<<<2048, 256, 0, stream>>>(mem, pos, qkb, 524288);  // CA key input

  for (int i = 0; i < 2; ++i) {
    const bf16* wsa = w_sa_qkv + (size_t)i * 196608;
    const float* sab = dec_sa_qkv_b + (size_t)i * 768;
    const bf16* wca = w_ca_qkv + (size_t)i * 196608;
    const float* cab = dec_ca_qkv_b + (size_t)i * 768;

    // self-attention
    add_bf16_kernel<<<160, 256, 0, stream>>>(tgt, query_embed, tqkb, 40960);
    gemm_f(tqkb, wsa,           sab,       qb, 640, 256, 256);
    gemm_f(tqkb, wsa + 65536,   sab + 256, kb, 640, 256, 256);
    gemm_f(tgtb, wsa + 131072,  sab + 512, vb, 640, 256, 256);
    attn_part<0><<<dim3(64, 1, 1), 256, 0, stream>>>(
        qb, kb, vb, nullptr, PO, pm, pl, 8, 8, 80, 80, 80, scale);
    attn_combine<<<20, 256, 0, stream>>>(PO, pm, pl, taob, 8, 8, 80, 1);
    gemm_f(taob, w_sa_out + (size_t)i * 65536, dec_sa_out_b + i * 256, tpr,
           640, 256, 256);
    ln_kernel<<<640, 256, 0, stream>>>(tgt, tpr, dec_ln1_g + i * 256,
                                       dec_ln1_b + i * 256, tgt, tgtb);
    // cross-attention
    add_bf16_kernel<<<160, 256, 0, stream>>>(tgt, query_embed, tqkb, 40960);
    gemm_f(tqkb, wca,          cab,       qb, 640, 256, 256);
    gemm_f(qkb,  wca + 65536,  cab + 256, kb, 8192, 256, 256);
    gemm_f(memb, wca + 131072, cab + 512, vb, 8192, 256, 256);
    attn_part<1><<<dim3(64, 1, 8), 256, 0, stream>>>(
        qb, kb, vb, cam_mask, PO, pm, pl, 8, 8, 80, 1024, 128, scale);
    attn_combine<<<20, 256, 0, stream>>>(PO, pm, pl, taob, 8, 8, 80, 8);
    gemm_f(taob, w_ca_out + (size_t)i * 65536, dec_ca_out_b + i * 256, tpr,
           640, 256, 256);
    ln_kernel<<<640, 256, 0, stream>>>(tgt, tpr, dec_ln2_g + i * 256,
                                       dec_ln2_b + i * 256, tgt, tgtb);
    // feed-forward
    gemm_bf_relu(tgtb, w_dec_ff1 + (size_t)i * 524288, dec_ff1_b + i * 2048, tffb,
                 640, 2048, 256);
    gemm_f(tffb, w_dec_ff2 + (size_t)i * 524288, dec_ff2_b + i * 256, tpr,
           640, 256, 2048);
    ln_kernel<<<640, 256, 0, stream>>>(tgt, tpr, dec_ln3_g + i * 256,
                                       dec_ln3_b + i * 256, tgt, tgtb);
  }

  // final norm -> fp32 output
  ln_kernel<<<640, 256, 0, stream>>>(tgt, nullptr, dec_norm_g, dec_norm_b,
                                     (float*)d_out, nullptr);
}

// Round 3
// 984.324 us; speedup vs baseline: 2.5919x; 1.4920x over previous
//
#include <hip/hip_runtime.h>
#include <hip/hip_bf16.h>
#include <cstdint>
#include <cstddef>

typedef __hip_bfloat16 bf16;
typedef float f4 __attribute__((ext_vector_type(4)));
typedef float f32x4 __attribute__((ext_vector_type(4)));
typedef short s8v __attribute__((ext_vector_type(8)));
typedef unsigned short u16x4 __attribute__((ext_vector_type(4)));

#define LN_EPS 1e-5f

// ------------------------------------------------------------------
// cast fp32 -> bf16
// ------------------------------------------------------------------
__global__ __launch_bounds__(256) void cast_kernel(const float* __restrict__ in,
                                                   bf16* __restrict__ out, int n4) {
  int i = blockIdx.x * 256 + threadIdx.x;
  if (i < n4) {
    f4 v = ((const f4*)in)[i];
    u16x4 o;
#pragma unroll
    for (int j = 0; j < 4; ++j) {
      bf16 h = __float2bfloat16(v[j]);
      o[j] = *reinterpret_cast<unsigned short*>(&h);
    }
    ((u16x4*)out)[i] = o;
  }
}

// ------------------------------------------------------------------
// add fp32 + fp32 -> bf16
// ------------------------------------------------------------------
__global__ __launch_bounds__(256) void add_bf16_kernel(const float* __restrict__ a,
                                                       const float* __restrict__ b,
                                                       bf16* __restrict__ out, int n4) {
  int i = blockIdx.x * 256 + threadIdx.x;
  if (i < n4) {
    f4 x = ((const f4*)a)[i];
    f4 y = ((const f4*)b)[i];
    u16x4 o;
#pragma unroll
    for (int j = 0; j < 4; ++j) {
      bf16 h = __float2bfloat16(x[j] + y[j]);
      o[j] = *reinterpret_cast<unsigned short*>(&h);
    }
    ((u16x4*)out)[i] = o;
  }
}

// ------------------------------------------------------------------
// MFMA GEMM: C[M,N] = A[M,K] @ W[N,K]^T + bias[N]
// MODE: 0 = f32 row-major, 1 = bf16 row-major, 2 = bf16 row-major + relu,
//       3 = bf16 head layout: row=(l*8+b), col=(sec*256 + h*32 + d) ->
//           Cb[sec*64*HL*32 + ((b*8+h)*HL + l)*32 + d]
// ------------------------------------------------------------------
template <int MODE>
__global__ __launch_bounds__(256, 2) void mfma_gemm(
    const bf16* __restrict__ A, const bf16* __restrict__ W,
    const float* __restrict__ bias, float* __restrict__ C,
    bf16* __restrict__ Cb, int M, int N, int K, int HL) {
  __shared__ __attribute__((aligned(16))) unsigned short As[128][72];
  __shared__ __attribute__((aligned(16))) unsigned short Ws[128][72];
  const int tid = threadIdx.x;
  const int lane = tid & 63, wave = tid >> 6;
  const int wr = wave >> 1, wc = wave & 1;
  const int bm = blockIdx.x * 128, bn = blockIdx.y * 128;
  const int srow = tid >> 3, scol = (tid & 7) * 8;
  const int fr = lane & 15, fk = (lane >> 4) * 8;

  f32x4 acc[4][4] = {};

  for (int k0 = 0; k0 < K; k0 += 64) {
    __syncthreads();
#pragma unroll
    for (int i = 0; i < 4; ++i) {
      int r = srow + 32 * i;
      *(s8v*)&As[r][scol] = *(const s8v*)(A + (size_t)(bm + r) * K + k0 + scol);
      *(s8v*)&Ws[r][scol] = *(const s8v*)(W + (size_t)(bn + r) * K + k0 + scol);
    }
    __syncthreads();
#pragma unroll
    for (int ks = 0; ks < 2; ++ks) {
      int kc = ks * 32 + fk;
      s8v a[4], b[4];
#pragma unroll
      for (int mi = 0; mi < 4; ++mi)
        a[mi] = *(const s8v*)&As[wr * 64 + mi * 16 + fr][kc];
#pragma unroll
      for (int ni = 0; ni < 4; ++ni)
        b[ni] = *(const s8v*)&Ws[wc * 64 + ni * 16 + fr][kc];
#pragma unroll
      for (int mi = 0; mi < 4; ++mi)
#pragma unroll
        for (int ni = 0; ni < 4; ++ni)
          acc[mi][ni] = __builtin_amdgcn_mfma_f32_16x16x32_bf16(
              a[mi], b[ni], acc[mi][ni], 0, 0, 0);
    }
  }

  const int r0 = (lane >> 4) * 4;
#pragma unroll
  for (int mi = 0; mi < 4; ++mi) {
#pragma unroll
    for (int ni = 0; ni < 4; ++ni) {
      int col = bn + wc * 64 + ni * 16 + fr;
      float bv = bias[col];
#pragma unroll
      for (int r = 0; r < 4; ++r) {
        int row = bm + wr * 64 + mi * 16 + r0 + r;
        float t = acc[mi][ni][r] + bv;
        if (MODE == 2) t = fmaxf(t, 0.f);
        if (MODE == 0) {
          C[(size_t)row * N + col] = t;
        } else if (MODE == 3) {
          int l = row >> 3, bb = row & 7;
          int sec = col >> 8, hh = (col >> 5) & 7, d = col & 31;
          Cb[(size_t)sec * ((size_t)64 * HL * 32) +
             ((size_t)(bb * 8 + hh) * HL + l) * 32 + d] = __float2bfloat16(t);
        } else {
          Cb[(size_t)row * N + col] = __float2bfloat16(t);
        }
      }
    }
  }
}

// ------------------------------------------------------------------
// MFMA flash attention.
// Q,K,V bf16 head layout (64, L|S, 32). O bf16 (L*8, 256).
// bias optional fp32 (8, L, S) (requires S % 64 == 0 when used).
// grid (64, ceil(L/64)), block 256 (4 waves, 16 q-rows/wave).
// ------------------------------------------------------------------
template <int HAS_BIAS>
__global__ __launch_bounds__(256) void attn_mfma(
    const bf16* __restrict__ Qh, const bf16* __restrict__ Kh,
    const bf16* __restrict__ Vh, const float* __restrict__ bias,
    bf16* __restrict__ O, int L, int S, float scale) {
  __shared__ __attribute__((aligned(16))) unsigned short Ks[64][40];
  __shared__ __attribute__((aligned(16))) unsigned short Vt[32][88];
  __shared__ __attribute__((aligned(16))) unsigned short Ps[4][16][72];
  const int tid = threadIdx.x;
  const int lane = tid & 63, wave = tid >> 6;
  const int fr = lane & 15, fo = lane >> 4;
  const int bh = blockIdx.x;
  const int b = bh >> 3, h = bh & 7;
  const int q0 = blockIdx.y * 64 + wave * 16;

  // Q fragment: A[row=q][k=d], lane: row=fr, k=fo*8..+7 (contiguous 16B)
  s8v qf = {};
  if (q0 + fr < L)
    qf = *(const s8v*)(Qh + ((size_t)bh * L + q0 + fr) * 32 + fo * 8);

  float m[4] = {-1e30f, -1e30f, -1e30f, -1e30f};
  float lsum[4] = {};
  f32x4 oacc[2] = {};

  const int srow = tid & 63, sc = (tid >> 6) * 8;
  const int qrow_base = q0 + fo * 4;

  for (int s0 = 0; s0 < S; s0 += 64) {
    __syncthreads();
    // stage K raw [key][d], V transposed [d][key]
    {
      s8v kv = {}, vv = {};
      if (s0 + srow < S) {
        size_t so = ((size_t)bh * S + s0 + srow) * 32 + sc;
        kv = *(const s8v*)(Kh + so);
        vv = *(const s8v*)(Vh + so);
      }
      *(s8v*)&Ks[srow][sc] = kv;
#pragma unroll
      for (int j = 0; j < 8; ++j)
        Vt[sc + j][srow] = ((unsigned short*)&vv)[j];
    }
    __syncthreads();

    // QK^T: 4 blocks of 16 keys
    f32x4 sa[4];
#pragma unroll
    for (int kb = 0; kb < 4; ++kb) {
      s8v bf = *(const s8v*)&Ks[kb * 16 + fr][fo * 8];
      f32x4 z = {};
      sa[kb] = __builtin_amdgcn_mfma_f32_16x16x32_bf16(qf, bf, z, 0, 0, 0);
    }

    // logits (lane holds: q = q0+fo*4+r, key = s0+kb*16+fr)
    float lg[4][4];
#pragma unroll
    for (int kb = 0; kb < 4; ++kb) {
      int key = s0 + kb * 16 + fr;
      bool kok = key < S;
#pragma unroll
      for (int r = 0; r < 4; ++r) {
        float t = sa[kb][r] * scale;
        if (HAS_BIAS) {
          int q = qrow_base + r;
          int qc = q < L ? q : L - 1;
          t += bias[((size_t)b * L + qc) * S + key];
        }
        lg[kb][r] = kok ? t : -1e30f;
      }
    }

    // tile max, reduce across the 16 key-lanes
    float tm[4];
#pragma unroll
    for (int r = 0; r < 4; ++r)
      tm[r] = fmaxf(fmaxf(lg[0][r], lg[1][r]), fmaxf(lg[2][r], lg[3][r]));
#pragma unroll
    for (int off = 1; off <= 8; off <<= 1)
#pragma unroll
      for (int r = 0; r < 4; ++r)
        tm[r] = fmaxf(tm[r], __shfl_xor(tm[r], off, 64));

    // online softmax update
    float pr[4][4];
#pragma unroll
    for (int r = 0; r < 4; ++r) {
      float nm = fmaxf(m[r], tm[r]);
      float rs = __expf(m[r] - nm);
      m[r] = nm;
      lsum[r] *= rs;
      oacc[0][r] *= rs;
      oacc[1][r] *= rs;
      float ps = 0.f;
#pragma unroll
      for (int kb = 0; kb < 4; ++kb) {
        float p = __expf(lg[kb][r] - nm);
        pr[kb][r] = p;
        ps += p;
      }
      lsum[r] += ps;
    }

    // stage P (per-wave buffer; same-wave write->read, no barrier needed)
#pragma unroll
    for (int kb = 0; kb < 4; ++kb)
#pragma unroll
      for (int r = 0; r < 4; ++r) {
        bf16 hp = __float2bfloat16(pr[kb][r]);
        Ps[wave][fo * 4 + r][kb * 16 + fr] = *(unsigned short*)&hp;
      }

    // PV: O[q][d] += P[q][key] * V[key][d]
#pragma unroll
    for (int ks = 0; ks < 2; ++ks) {
      s8v af = *(const s8v*)&Ps[wave][fr][ks * 32 + fo * 8];
#pragma unroll
      for (int dh = 0; dh < 2; ++dh) {
        s8v vf = *(const s8v*)&Vt[dh * 16 + fr][ks * 32 + fo * 8];
        oacc[dh] = __builtin_amdgcn_mfma_f32_16x16x32_bf16(af, vf, oacc[dh], 0, 0, 0);
      }
    }
  }

  // full row-sum across the 16 key-lanes
#pragma unroll
  for (int off = 1; off <= 8; off <<= 1)
#pragma unroll
    for (int r = 0; r < 4; ++r)
      lsum[r] += __shfl_xor(lsum[r], off, 64);

  // write O (row q, cols h*32 + {fr, 16+fr})
#pragma unroll
  for (int r = 0; r < 4; ++r) {
    int q = qrow_base + r;
    if (q < L) {
      float inv = 1.f / lsum[r];
      bf16* op = O + ((size_t)q * 8 + b) * 256 + h * 32;
      op[fr] = __float2bfloat16(oacc[0][r] * inv);
      op[16 + fr] = __float2bfloat16(oacc[1][r] * inv);
    }
  }
}

// ------------------------------------------------------------------
// LayerNorm over last dim (256): out = LN(x + res)*g + b ; dual output
// ------------------------------------------------------------------
__global__ __launch_bounds__(256) void ln_kernel(
    const float* __restrict__ x, const float* __restrict__ res,
    const float* __restrict__ g, const float* __restrict__ b,
    float* __restrict__ out, bf16* __restrict__ outb) {
  const int row = blockIdx.x, tid = threadIdx.x;
  size_t idx = (size_t)row * 256 + tid;
  float v = x[idx];
  if (res) v += res[idx];
  float s = v, s2 = v * v;
#pragma unroll
  for (int off = 32; off >= 1; off >>= 1) {
    s += __shfl_down(s, off);
    s2 += __shfl_down(s2, off);
  }
  __shared__ float red[8];
  int wv = tid >> 6;
  if ((tid & 63) == 0) { red[wv] = s; red[4 + wv] = s2; }
  __syncthreads();
  if (tid == 0) {
    float ts = red[0] + red[1] + red[2] + red[3];
    float ts2 = red[4] + red[5] + red[6] + red[7];
    float mu = ts * (1.f / 256.f);
    float var = ts2 * (1.f / 256.f) - mu * mu;
    red[0] = mu;
    red[1] = rsqrtf(var + LN_EPS);
  }
  __syncthreads();
  float y = (v - red[0]) * red[1] * g[tid] + b[tid];
  if (out) out[idx] = y;
  if (outb) outb[idx] = __float2bfloat16(y);
}

// ------------------------------------------------------------------
// Host orchestration
// ------------------------------------------------------------------
extern "C" void kernel_launch(void* const* d_in, const int* in_sizes, int n_in,
                              void* d_out, int out_size, void* d_ws, size_t ws_size,
                              hipStream_t stream) {
  const float* src         = (const float*)d_in[0];
  const float* pos         = (const float*)d_in[1];
  const float* query_embed = (const float*)d_in[2];
  const float* cam_mask    = (const float*)d_in[3];
  const float* enc_qkv_w   = (const float*)d_in[4];
  const float* enc_qkv_b   = (const float*)d_in[5];
  const float* enc_out_w   = (const float*)d_in[6];
  const float* enc_out_b   = (const float*)d_in[7];
  const float* enc_ln1_g   = (const float*)d_in[8];
  const float* enc_ln1_b   = (const float*)d_in[9];
  const float* enc_ff1_w   = (const float*)d_in[10];
  const float* enc_ff1_b   = (const float*)d_in[11];
  const float* enc_ff2_w   = (const float*)d_in[12];
  const float* enc_ff2_b   = (const float*)d_in[13];
  const float* enc_ln2_g   = (const float*)d_in[14];
  const float* enc_ln2_b   = (const float*)d_in[15];
  const float* dec_sa_qkv_w= (const float*)d_in[16];
  const float* dec_sa_qkv_b= (const float*)d_in[17];
  const float* dec_sa_out_w= (const float*)d_in[18];
  const float* dec_sa_out_b= (const float*)d_in[19];
  const float* dec_ln1_g   = (const float*)d_in[20];
  const float* dec_ln1_b   = (const float*)d_in[21];
  const float* dec_ca_qkv_w= (const float*)d_in[22];
  const float* dec_ca_qkv_b= (const float*)d_in[23];
  const float* dec_ca_out_w= (const float*)d_in[24];
  const float* dec_ca_out_b= (const float*)d_in[25];
  const float* dec_ln2_g   = (const float*)d_in[26];
  const float* dec_ln2_b   = (const float*)d_in[27];
  const float* dec_ff1_w   = (const float*)d_in[28];
  const float* dec_ff1_b   = (const float*)d_in[29];
  const float* dec_ff2_w   = (const float*)d_in[30];
  const float* dec_ff2_b   = (const float*)d_in[31];
  const float* dec_ln3_g   = (const float*)d_in[32];
  const float* dec_ln3_b   = (const float*)d_in[33];
  const float* dec_norm_g  = (const float*)d_in[34];
  const float* dec_norm_b  = (const float*)d_in[35];

  // ---------------- workspace layout ----------------
  size_t off = 0;
  char* base = (char*)d_ws;
  auto af = [&](size_t n) { float* p = (float*)(base + off); off += n * 4; return p; };
  auto ab = [&](size_t n) { bf16*  p = (bf16*)(base + off);  off += n * 2; return p; };

  float* mem  = af(2097152);
  float* r1   = af(2097152);
  float* tgt  = af(163840);
  float* tpr  = af(163840);
  bf16* memb  = ab(2097152);
  bf16* qkb   = ab(2097152);
  bf16* aob   = ab(2097152);
  bf16* ffb   = ab(16777216);
  bf16* bufQ  = ab(4194304);   // Q section + batched-K section
  bf16* bufK  = ab(2097152);   // standalone K (cross-attn)
  bf16* bufV  = ab(2097152);
  bf16* tgtb  = ab(163840);
  bf16* tqkb  = ab(163840);
  bf16* taob  = ab(163840);
  bf16* tffb  = ab(1310720);
  bf16* w_enc_qkv = ab(393216);
  bf16* w_enc_out = ab(131072);
  bf16* w_enc_ff1 = ab(1048576);
  bf16* w_enc_ff2 = ab(1048576);
  bf16* w_sa_qkv  = ab(393216);
  bf16* w_sa_out  = ab(131072);
  bf16* w_ca_qkv  = ab(393216);
  bf16* w_ca_out  = ab(131072);
  bf16* w_dec_ff1 = ab(1048576);
  bf16* w_dec_ff2 = ab(1048576);

  const float scale = 0.17677669529663687f;  // 1/sqrt(32)

  auto cast = [&](const float* in, bf16* out, int n) {
    int n4 = n / 4;
    cast_kernel<<<(n4 + 255) / 256, 256, 0, stream>>>(in, out, n4);
  };
  auto gemm_f = [&](const bf16* A, const bf16* W, const float* bias, float* C,
                    int M, int N, int K) {
    mfma_gemm<0><<<dim3(M / 128, N / 128), 256, 0, stream>>>(
        A, W, bias, C, nullptr, M, N, K, 0);
  };
  auto gemm_bf_relu = [&](const bf16* A, const bf16* W, const float* bias, bf16* Cb,
                          int M, int N, int K) {
    mfma_gemm<2><<<dim3(M / 128, N / 128), 256, 0, stream>>>(
        A, W, bias, nullptr, Cb, M, N, K, 0);
  };
  auto gemm_head = [&](const bf16* A, const bf16* W, const float* bias, bf16* Cb,
                       int M, int N, int K, int HL) {
    mfma_gemm<3><<<dim3(M / 128, N / 128), 256, 0, stream>>>(
        A, W, bias, nullptr, Cb, M, N, K, HL);
  };

  // weight casts (fp32 -> bf16)
  cast(enc_qkv_w, w_enc_qkv, 393216);
  cast(enc_out_w, w_enc_out, 131072);
  cast(enc_ff1_w, w_enc_ff1, 1048576);
  cast(enc_ff2_w, w_enc_ff2, 1048576);
  cast(dec_sa_qkv_w, w_sa_qkv, 393216);
  cast(dec_sa_out_w, w_sa_out, 131072);
  cast(dec_ca_qkv_w, w_ca_qkv, 393216);
  cast(dec_ca_out_w, w_ca_out, 131072);
  cast(dec_ff1_w, w_dec_ff1, 1048576);
  cast(dec_ff2_w, w_dec_ff2, 1048576);

  // mem = src (fp32 + bf16)
  hipMemcpyAsync(mem, src, (size_t)2097152 * 4, hipMemcpyDeviceToDevice, stream);
  cast(src, memb, 2097152);

  // ---------------- encoder ----------------
  for (int i = 0; i < 2; ++i) {
    const bf16* wq = w_enc_qkv + (size_t)i * 196608;
    const float* qkvb = enc_qkv_b + (size_t)i * 768;
    add_bf16_kernel<<<2048, 256, 0, stream>>>(mem, pos, qkb, 524288);
    gemm_head(qkb, wq, qkvb, bufQ, 8192, 512, 256, 1024);            // Q + K
    gemm_head(memb, wq + 131072, qkvb + 512, bufV, 8192, 256, 256, 1024);  // V
    attn_mfma<0><<<dim3(64, 16), 256, 0, stream>>>(
        bufQ, bufQ + 2097152, bufV, nullptr, aob, 1024, 1024, scale);
    gemm_f(aob, w_enc_out + (size_t)i * 65536, enc_out_b + i * 256, r1,
           8192, 256, 256);
    ln_kernel<<<8192, 256, 0, stream>>>(mem, r1, enc_ln1_g + i * 256,
                                        enc_ln1_b + i * 256, mem, memb);
    gemm_bf_relu(memb, w_enc_ff1 + (size_t)i * 524288, enc_ff1_b + i * 2048, ffb,
                 8192, 2048, 256);
    gemm_f(ffb, w_enc_ff2 + (size_t)i * 524288, enc_ff2_b + i * 256, r1,
           8192, 256, 2048);
    ln_kernel<<<8192, 256, 0, stream>>>(mem, r1, enc_ln2_g + i * 256,
                                        enc_ln2_b + i * 256, mem, memb);
  }

  // ---------------- decoder ----------------
  hipMemsetAsync(tgt, 0, (size_t)163840 * 4, stream);
  hipMemsetAsync(tgtb, 0, (size_t)163840 * 2, stream);
  add_bf16_kernel<<<2048, 256, 0, stream>>>(mem, pos, qkb, 524288);  // CA key input

  for (int i = 0; i < 2; ++i) {
    const bf16* wsa = w_sa_qkv + (size_t)i * 196608;
    const float* sab = dec_sa_qkv_b + (size_t)i * 768;
    const bf16* wca = w_ca_qkv + (size_t)i * 196608;
    const float* cab = dec_ca_qkv_b + (size_t)i * 768;

    // self-attention
    add_bf16_kernel<<<160, 256, 0, stream>>>(tgt, query_embed, tqkb, 40960);
    gemm_head(tqkb, wsa, sab, bufQ, 640, 512, 256, 80);              // Q + K
    gemm_head(tgtb, wsa + 131072, sab + 512, bufV, 640, 256, 256, 80);  // V
    attn_mfma<0><<<dim3(64, 2), 256, 0, stream>>>(
        bufQ, bufQ + 163840, bufV, nullptr, taob, 80, 80, scale);
    gemm_f(taob, w_sa_out + (size_t)i * 65536, dec_sa_out_b + i * 256, tpr,
           640, 256, 256);
    ln_kernel<<<640, 256, 0, stream>>>(tgt, tpr, dec_ln1_g + i * 256,
                                       dec_ln1_b + i * 256, tgt, tgtb);
    // cross-attention
    add_bf16_kernel<<<160, 256, 0, stream>>>(tgt, query_embed, tqkb, 40960);
    gemm_head(tqkb, wca, cab, bufQ, 640, 256, 256, 80);              // Q
    gemm_head(qkb, wca + 65536, cab + 256, bufK, 8192, 256, 256, 1024);   // K
    gemm_head(memb, wca + 131072, cab + 512, bufV, 8192, 256, 256, 1024); // V
    attn_mfma<1><<<dim3(64, 2), 256, 0, stream>>>(
        bufQ, bufK, bufV, cam_mask, taob, 80, 1024, scale);
    gemm_f(taob, w_ca_out + (size_t)i * 65536, dec_ca_out_b + i * 256, tpr,
           640, 256, 256);
    ln_kernel<<<640, 256, 0, stream>>>(tgt, tpr, dec_ln2_g + i * 256,
                                       dec_ln2_b + i * 256, tgt, tgtb);
    // feed-forward
    gemm_bf_relu(tgtb, w_dec_ff1 + (size_t)i * 524288, dec_ff1_b + i * 2048, tffb,
                 640, 2048, 256);
    gemm_f(tffb, w_dec_ff2 + (size_t)i * 524288, dec_ff2_b + i * 256, tpr,
           640, 256, 2048);
    ln_kernel<<<640, 256, 0, stream>>>(tgt, tpr, dec_ln3_g + i * 256,
                                       dec_ln3_b + i * 256, tgt, tgtb);
  }

  // final norm -> fp32 output
  ln_kernel<<<640, 256, 0, stream>>>(tgt, nullptr, dec_norm_g, dec_norm_b,
                                     (float*)d_out, nullptr);
}

// Round 4
// 491.845 us; speedup vs baseline: 5.1871x; 2.0013x over previous
//
#include <hip/hip_runtime.h>
#include <hip/hip_bf16.h>
#include <cstdint>
#include <cstddef>

typedef __hip_bfloat16 bf16;
typedef float f4 __attribute__((ext_vector_type(4)));
typedef float f32x4 __attribute__((ext_vector_type(4)));
typedef short s8v __attribute__((ext_vector_type(8)));
typedef unsigned short u16x4 __attribute__((ext_vector_type(4)));

#define LN_EPS 1e-5f

// ------------------------------------------------------------------
// fused multi-segment cast fp32 -> bf16
// ------------------------------------------------------------------
#define NCAST 11
struct CastArgs {
  const float* in[NCAST];
  bf16* out[NCAST];
  int end4[NCAST];   // cumulative end (in float4 units)
  int nseg;
};

__global__ __launch_bounds__(256) void cast_multi(CastArgs a, int total4) {
  int i = blockIdx.x * 256 + threadIdx.x;
  if (i >= total4) return;
  int s = 0;
  while (i >= a.end4[s]) ++s;
  int j = i - (s ? a.end4[s - 1] : 0);
  f4 v = ((const f4*)a.in[s])[j];
  u16x4 o;
#pragma unroll
  for (int c = 0; c < 4; ++c) {
    bf16 h = __float2bfloat16(v[c]);
    o[c] = *reinterpret_cast<unsigned short*>(&h);
  }
  ((u16x4*)a.out[s])[j] = o;
}

// ------------------------------------------------------------------
// add fp32 + fp32 -> bf16
// ------------------------------------------------------------------
__global__ __launch_bounds__(256) void add_bf16_kernel(const float* __restrict__ a,
                                                       const float* __restrict__ b,
                                                       bf16* __restrict__ out, int n4) {
  int i = blockIdx.x * 256 + threadIdx.x;
  if (i < n4) {
    f4 x = ((const f4*)a)[i];
    f4 y = ((const f4*)b)[i];
    u16x4 o;
#pragma unroll
    for (int j = 0; j < 4; ++j) {
      bf16 h = __float2bfloat16(x[j] + y[j]);
      o[j] = *reinterpret_cast<unsigned short*>(&h);
    }
    ((u16x4*)out)[i] = o;
  }
}

// ------------------------------------------------------------------
// MFMA GEMM: C[M,N] = A[M,K] @ W[N,K]^T (+ bias[N])
// TB = square tile size (64 or 128), 256 threads (4 waves as 2x2).
// MODE: 0 = f32 row-major (+bias)
//       2 = bf16 row-major + relu (+bias)
//       3 = bf16 head layout (+bias): row=(l*8+b), col=(sec*256+h*32+d) ->
//           Cb[sec*64*HL*32 + ((b*8+h)*HL + l)*32 + d]
//       4 = f32 partial (split-K, NO bias): C + z*M*N
// SPLITK: blockIdx.z selects K-chunk of size K/SPLITK.
// ------------------------------------------------------------------
template <int TB, int MODE, int SPLITK>
__global__ __launch_bounds__(256, 2) void mfma_gemm(
    const bf16* __restrict__ A, const bf16* __restrict__ W,
    const float* __restrict__ bias, float* __restrict__ C,
    bf16* __restrict__ Cb, int M, int N, int K, int HL) {
  constexpr int WM = TB / 2, WN = TB / 2;
  constexpr int MR = WM / 16, NR = WN / 16;
  constexpr int AIT = TB / 32;
  __shared__ __attribute__((aligned(16))) unsigned short As[TB][72];
  __shared__ __attribute__((aligned(16))) unsigned short Ws[TB][72];
  const int tid = threadIdx.x;
  const int lane = tid & 63, wave = tid >> 6;
  const int wr = wave >> 1, wc = wave & 1;
  const int bm = blockIdx.x * TB, bn = blockIdx.y * TB;
  const int srow = tid >> 3, scol = (tid & 7) * 8;
  const int fr = lane & 15, fk = (lane >> 4) * 8;

  const int kchunk = K / SPLITK;
  const int kbeg = (SPLITK > 1) ? blockIdx.z * kchunk : 0;

  f32x4 acc[MR][NR] = {};

  for (int k0 = kbeg; k0 < kbeg + kchunk; k0 += 64) {
    __syncthreads();
#pragma unroll
    for (int i = 0; i < AIT; ++i) {
      int r = srow + 32 * i;
      *(s8v*)&As[r][scol] = *(const s8v*)(A + (size_t)(bm + r) * K + k0 + scol);
      *(s8v*)&Ws[r][scol] = *(const s8v*)(W + (size_t)(bn + r) * K + k0 + scol);
    }
    __syncthreads();
#pragma unroll
    for (int ks = 0; ks < 2; ++ks) {
      int kc = ks * 32 + fk;
      s8v a[MR], b[NR];
#pragma unroll
      for (int mi = 0; mi < MR; ++mi)
        a[mi] = *(const s8v*)&As[wr * WM + mi * 16 + fr][kc];
#pragma unroll
      for (int ni = 0; ni < NR; ++ni)
        b[ni] = *(const s8v*)&Ws[wc * WN + ni * 16 + fr][kc];
#pragma unroll
      for (int mi = 0; mi < MR; ++mi)
#pragma unroll
        for (int ni = 0; ni < NR; ++ni)
          acc[mi][ni] = __builtin_amdgcn_mfma_f32_16x16x32_bf16(
              a[mi], b[ni], acc[mi][ni], 0, 0, 0);
    }
  }

  const int r0 = (lane >> 4) * 4;
  float* Cz = (MODE == 4) ? C + (size_t)blockIdx.z * M * N : C;
#pragma unroll
  for (int mi = 0; mi < MR; ++mi) {
#pragma unroll
    for (int ni = 0; ni < NR; ++ni) {
      int col = bn + wc * WN + ni * 16 + fr;
      float bv = (MODE == 4) ? 0.f : bias[col];
#pragma unroll
      for (int r = 0; r < 4; ++r) {
        int row = bm + wr * WM + mi * 16 + r0 + r;
        float t = acc[mi][ni][r] + bv;
        if (MODE == 2) t = fmaxf(t, 0.f);
        if (MODE == 0) {
          C[(size_t)row * N + col] = t;
        } else if (MODE == 4) {
          Cz[(size_t)row * N + col] = t;
        } else if (MODE == 3) {
          int l = row >> 3, bb = row & 7;
          int sec = col >> 8, hh = (col >> 5) & 7, d = col & 31;
          Cb[(size_t)sec * ((size_t)64 * HL * 32) +
             ((size_t)(bb * 8 + hh) * HL + l) * 32 + d] = __float2bfloat16(t);
        } else {
          Cb[(size_t)row * N + col] = __float2bfloat16(t);
        }
      }
    }
  }
}

// ------------------------------------------------------------------
// MFMA flash attention.
// Q,K,V bf16 head layout (64, L|S, 32). O bf16 (L*8, 256).
// bias optional fp32 (8, L, S) (requires S % 64 == 0 when used).
// grid (64, ceil(L/64)), block 256 (4 waves, 16 q-rows/wave).
// ------------------------------------------------------------------
template <int HAS_BIAS>
__global__ __launch_bounds__(256) void attn_mfma(
    const bf16* __restrict__ Qh, const bf16* __restrict__ Kh,
    const bf16* __restrict__ Vh, const float* __restrict__ bias,
    bf16* __restrict__ O, int L, int S, float scale) {
  __shared__ __attribute__((aligned(16))) unsigned short Ks[64][40];
  __shared__ __attribute__((aligned(16))) unsigned short Vt[32][88];
  __shared__ __attribute__((aligned(16))) unsigned short Ps[4][16][72];
  const int tid = threadIdx.x;
  const int lane = tid & 63, wave = tid >> 6;
  const int fr = lane & 15, fo = lane >> 4;
  const int bh = blockIdx.x;
  const int b = bh >> 3, h = bh & 7;
  const int q0 = blockIdx.y * 64 + wave * 16;

  s8v qf = {};
  if (q0 + fr < L)
    qf = *(const s8v*)(Qh + ((size_t)bh * L + q0 + fr) * 32 + fo * 8);

  float m[4] = {-1e30f, -1e30f, -1e30f, -1e30f};
  float lsum[4] = {};
  f32x4 oacc[2] = {};

  const int srow = tid & 63, sc = (tid >> 6) * 8;
  const int qrow_base = q0 + fo * 4;

  for (int s0 = 0; s0 < S; s0 += 64) {
    __syncthreads();
    {
      s8v kv = {}, vv = {};
      if (s0 + srow < S) {
        size_t so = ((size_t)bh * S + s0 + srow) * 32 + sc;
        kv = *(const s8v*)(Kh + so);
        vv = *(const s8v*)(Vh + so);
      }
      *(s8v*)&Ks[srow][sc] = kv;
#pragma unroll
      for (int j = 0; j < 8; ++j)
        Vt[sc + j][srow] = ((unsigned short*)&vv)[j];
    }
    __syncthreads();

    f32x4 sa[4];
#pragma unroll
    for (int kb = 0; kb < 4; ++kb) {
      s8v bf = *(const s8v*)&Ks[kb * 16 + fr][fo * 8];
      f32x4 z = {};
      sa[kb] = __builtin_amdgcn_mfma_f32_16x16x32_bf16(qf, bf, z, 0, 0, 0);
    }

    float lg[4][4];
#pragma unroll
    for (int kb = 0; kb < 4; ++kb) {
      int key = s0 + kb * 16 + fr;
      bool kok = key < S;
#pragma unroll
      for (int r = 0; r < 4; ++r) {
        float t = sa[kb][r] * scale;
        if (HAS_BIAS) {
          int q = qrow_base + r;
          int qc = q < L ? q : L - 1;
          t += bias[((size_t)b * L + qc) * S + key];
        }
        lg[kb][r] = kok ? t : -1e30f;
      }
    }

    float tm[4];
#pragma unroll
    for (int r = 0; r < 4; ++r)
      tm[r] = fmaxf(fmaxf(lg[0][r], lg[1][r]), fmaxf(lg[2][r], lg[3][r]));
#pragma unroll
    for (int off = 1; off <= 8; off <<= 1)
#pragma unroll
      for (int r = 0; r < 4; ++r)
        tm[r] = fmaxf(tm[r], __shfl_xor(tm[r], off, 64));

    float pr[4][4];
#pragma unroll
    for (int r = 0; r < 4; ++r) {
      float nm = fmaxf(m[r], tm[r]);
      float rs = __expf(m[r] - nm);
      m[r] = nm;
      lsum[r] *= rs;
      oacc[0][r] *= rs;
      oacc[1][r] *= rs;
      float ps = 0.f;
#pragma unroll
      for (int kb = 0; kb < 4; ++kb) {
        float p = __expf(lg[kb][r] - nm);
        pr[kb][r] = p;
        ps += p;
      }
      lsum[r] += ps;
    }

#pragma unroll
    for (int kb = 0; kb < 4; ++kb)
#pragma unroll
      for (int r = 0; r < 4; ++r) {
        bf16 hp = __float2bfloat16(pr[kb][r]);
        Ps[wave][fo * 4 + r][kb * 16 + fr] = *(unsigned short*)&hp;
      }

#pragma unroll
    for (int ks = 0; ks < 2; ++ks) {
      s8v af = *(const s8v*)&Ps[wave][fr][ks * 32 + fo * 8];
#pragma unroll
      for (int dh = 0; dh < 2; ++dh) {
        s8v vf = *(const s8v*)&Vt[dh * 16 + fr][ks * 32 + fo * 8];
        oacc[dh] = __builtin_amdgcn_mfma_f32_16x16x32_bf16(af, vf, oacc[dh], 0, 0, 0);
      }
    }
  }

#pragma unroll
  for (int off = 1; off <= 8; off <<= 1)
#pragma unroll
    for (int r = 0; r < 4; ++r)
      lsum[r] += __shfl_xor(lsum[r], off, 64);

#pragma unroll
  for (int r = 0; r < 4; ++r) {
    int q = qrow_base + r;
    if (q < L) {
      float inv = 1.f / lsum[r];
      bf16* op = O + ((size_t)q * 8 + b) * 256 + h * 32;
      op[fr] = __float2bfloat16(oacc[0][r] * inv);
      op[16 + fr] = __float2bfloat16(oacc[1][r] * inv);
    }
  }
}

// ------------------------------------------------------------------
// LayerNorm over last dim (256): v = x (+res) (+Σ parts) (+gbias);
// out = LN(v)*g + b ; dual output (f32 + bf16)
// ------------------------------------------------------------------
__global__ __launch_bounds__(256) void ln_kernel(
    const float* __restrict__ x, const float* __restrict__ res,
    const float* __restrict__ parts, int nparts, int pstride,
    const float* __restrict__ gbias,
    const float* __restrict__ g, const float* __restrict__ b,
    float* __restrict__ out, bf16* __restrict__ outb) {
  const int row = blockIdx.x, tid = threadIdx.x;
  size_t idx = (size_t)row * 256 + tid;
  float v = x[idx];
  if (res) v += res[idx];
  if (parts) {
    for (int z = 0; z < nparts; ++z) v += parts[(size_t)z * pstride + idx];
  }
  if (gbias) v += gbias[tid];
  float s = v, s2 = v * v;
#pragma unroll
  for (int off = 32; off >= 1; off >>= 1) {
    s += __shfl_down(s, off);
    s2 += __shfl_down(s2, off);
  }
  __shared__ float red[8];
  int wv = tid >> 6;
  if ((tid & 63) == 0) { red[wv] = s; red[4 + wv] = s2; }
  __syncthreads();
  if (tid == 0) {
    float ts = red[0] + red[1] + red[2] + red[3];
    float ts2 = red[4] + red[5] + red[6] + red[7];
    float mu = ts * (1.f / 256.f);
    float var = ts2 * (1.f / 256.f) - mu * mu;
    red[0] = mu;
    red[1] = rsqrtf(var + LN_EPS);
  }
  __syncthreads();
  float y = (v - red[0]) * red[1] * g[tid] + b[tid];
  if (out) out[idx] = y;
  if (outb) outb[idx] = __float2bfloat16(y);
}

// ------------------------------------------------------------------
// Host orchestration
// ------------------------------------------------------------------
extern "C" void kernel_launch(void* const* d_in, const int* in_sizes, int n_in,
                              void* d_out, int out_size, void* d_ws, size_t ws_size,
                              hipStream_t stream) {
  const float* src         = (const float*)d_in[0];
  const float* pos         = (const float*)d_in[1];
  const float* query_embed = (const float*)d_in[2];
  const float* cam_mask    = (const float*)d_in[3];
  const float* enc_qkv_w   = (const float*)d_in[4];
  const float* enc_qkv_b   = (const float*)d_in[5];
  const float* enc_out_w   = (const float*)d_in[6];
  const float* enc_out_b   = (const float*)d_in[7];
  const float* enc_ln1_g   = (const float*)d_in[8];
  const float* enc_ln1_b   = (const float*)d_in[9];
  const float* enc_ff1_w   = (const float*)d_in[10];
  const float* enc_ff1_b   = (const float*)d_in[11];
  const float* enc_ff2_w   = (const float*)d_in[12];
  const float* enc_ff2_b   = (const float*)d_in[13];
  const float* enc_ln2_g   = (const float*)d_in[14];
  const float* enc_ln2_b   = (const float*)d_in[15];
  const float* dec_sa_qkv_w= (const float*)d_in[16];
  const float* dec_sa_qkv_b= (const float*)d_in[17];
  const float* dec_sa_out_w= (const float*)d_in[18];
  const float* dec_sa_out_b= (const float*)d_in[19];
  const float* dec_ln1_g   = (const float*)d_in[20];
  const float* dec_ln1_b   = (const float*)d_in[21];
  const float* dec_ca_qkv_w= (const float*)d_in[22];
  const float* dec_ca_qkv_b= (const float*)d_in[23];
  const float* dec_ca_out_w= (const float*)d_in[24];
  const float* dec_ca_out_b= (const float*)d_in[25];
  const float* dec_ln2_g   = (const float*)d_in[26];
  const float* dec_ln2_b   = (const float*)d_in[27];
  const float* dec_ff1_w   = (const float*)d_in[28];
  const float* dec_ff1_b   = (const float*)d_in[29];
  const float* dec_ff2_w   = (const float*)d_in[30];
  const float* dec_ff2_b   = (const float*)d_in[31];
  const float* dec_ln3_g   = (const float*)d_in[32];
  const float* dec_ln3_b   = (const float*)d_in[33];
  const float* dec_norm_g  = (const float*)d_in[34];
  const float* dec_norm_b  = (const float*)d_in[35];

  // ---------------- workspace layout ----------------
  size_t off = 0;
  char* base = (char*)d_ws;
  auto af = [&](size_t n) { float* p = (float*)(base + off); off += n * 4; return p; };
  auto ab = [&](size_t n) { bf16*  p = (bf16*)(base + off);  off += n * 2; return p; };

  float* mem  = af(2097152);
  float* r1   = af(2097152);
  float* PO   = af(8388608);   // split-K partials (4 x 8192*256)
  float* tgt  = af(163840);
  float* tpr  = af(163840);
  bf16* memb  = ab(2097152);
  bf16* qkb   = ab(2097152);
  bf16* aob   = ab(2097152);
  bf16* ffb   = ab(16777216);
  bf16* bufQ  = ab(4194304);   // Q section + batched-K section
  bf16* bufK  = ab(2097152);
  bf16* bufV  = ab(2097152);
  bf16* tgtb  = ab(163840);
  bf16* tqkb  = ab(163840);
  bf16* taob  = ab(163840);
  bf16* tffb  = ab(1310720);
  bf16* w_enc_qkv = ab(393216);
  bf16* w_enc_out = ab(131072);
  bf16* w_enc_ff1 = ab(1048576);
  bf16* w_enc_ff2 = ab(1048576);
  bf16* w_sa_qkv  = ab(393216);
  bf16* w_sa_out  = ab(131072);
  bf16* w_ca_qkv  = ab(393216);
  bf16* w_ca_out  = ab(131072);
  bf16* w_dec_ff1 = ab(1048576);
  bf16* w_dec_ff2 = ab(1048576);

  const float scale = 0.17677669529663687f;  // 1/sqrt(32)

  // ---- fused weight + src casts ----
  {
    CastArgs ca;
    const float* ins[NCAST] = {enc_qkv_w, enc_out_w, enc_ff1_w, enc_ff2_w,
                               dec_sa_qkv_w, dec_sa_out_w, dec_ca_qkv_w,
                               dec_ca_out_w, dec_ff1_w, dec_ff2_w, src};
    bf16* outs[NCAST] = {w_enc_qkv, w_enc_out, w_enc_ff1, w_enc_ff2,
                         w_sa_qkv, w_sa_out, w_ca_qkv,
                         w_ca_out, w_dec_ff1, w_dec_ff2, memb};
    int n4s[NCAST] = {98304, 32768, 262144, 262144, 98304, 32768, 98304,
                      32768, 262144, 262144, 524288};
    int acc = 0;
    for (int s = 0; s < NCAST; ++s) {
      ca.in[s] = ins[s]; ca.out[s] = outs[s];
      acc += n4s[s]; ca.end4[s] = acc;
    }
    ca.nseg = NCAST;
    cast_multi<<<(acc + 255) / 256, 256, 0, stream>>>(ca, acc);
  }
  hipMemcpyAsync(mem, src, (size_t)2097152 * 4, hipMemcpyDeviceToDevice, stream);

  // GEMM launch helpers
  auto g64_f = [&](const bf16* A, const bf16* W, const float* bias, float* C,
                   int M, int N, int K) {
    mfma_gemm<64, 0, 1><<<dim3(M / 64, N / 64), 256, 0, stream>>>(
        A, W, bias, C, nullptr, M, N, K, 0);
  };
  auto g64_head = [&](const bf16* A, const bf16* W, const float* bias, bf16* Cb,
                      int M, int N, int K, int HL) {
    mfma_gemm<64, 3, 1><<<dim3(M / 64, N / 64), 256, 0, stream>>>(
        A, W, bias, nullptr, Cb, M, N, K, HL);
  };
  auto g64_relu = [&](const bf16* A, const bf16* W, const float* bias, bf16* Cb,
                      int M, int N, int K) {
    mfma_gemm<64, 2, 1><<<dim3(M / 64, N / 64), 256, 0, stream>>>(
        A, W, bias, nullptr, Cb, M, N, K, 0);
  };
  auto g128_relu = [&](const bf16* A, const bf16* W, const float* bias, bf16* Cb,
                       int M, int N, int K) {
    mfma_gemm<128, 2, 1><<<dim3(M / 128, N / 128), 256, 0, stream>>>(
        A, W, bias, nullptr, Cb, M, N, K, 0);
  };

  // ---------------- encoder ----------------
  for (int i = 0; i < 2; ++i) {
    const bf16* wq = w_enc_qkv + (size_t)i * 196608;
    const float* qkvb = enc_qkv_b + (size_t)i * 768;
    add_bf16_kernel<<<2048, 256, 0, stream>>>(mem, pos, qkb, 524288);
    g64_head(qkb, wq, qkvb, bufQ, 8192, 512, 256, 1024);                  // Q + K
    g64_head(memb, wq + 131072, qkvb + 512, bufV, 8192, 256, 256, 1024);  // V
    attn_mfma<0><<<dim3(64, 16), 256, 0, stream>>>(
        bufQ, bufQ + 2097152, bufV, nullptr, aob, 1024, 1024, scale);
    g64_f(aob, w_enc_out + (size_t)i * 65536, enc_out_b + i * 256, r1,
          8192, 256, 256);
    ln_kernel<<<8192, 256, 0, stream>>>(mem, r1, nullptr, 0, 0, nullptr,
                                        enc_ln1_g + i * 256, enc_ln1_b + i * 256,
                                        mem, memb);
    g128_relu(memb, w_enc_ff1 + (size_t)i * 524288, enc_ff1_b + i * 2048, ffb,
              8192, 2048, 256);
    // FF2 split-K=4 -> fp32 partials, reduced inside LN
    mfma_gemm<128, 4, 4><<<dim3(64, 2, 4), 256, 0, stream>>>(
        ffb, w_enc_ff2 + (size_t)i * 524288, nullptr, PO, nullptr,
        8192, 256, 2048, 0);
    ln_kernel<<<8192, 256, 0, stream>>>(mem, nullptr, PO, 4, 2097152,
                                        enc_ff2_b + i * 256,
                                        enc_ln2_g + i * 256, enc_ln2_b + i * 256,
                                        mem, memb);
  }

  // ---------------- decoder ----------------
  hipMemsetAsync(tgt, 0, (size_t)163840 * 4, stream);
  hipMemsetAsync(tgtb, 0, (size_t)163840 * 2, stream);
  add_bf16_kernel<<<2048, 256, 0, stream>>>(mem, pos, qkb, 524288);  // CA key input

  for (int i = 0; i < 2; ++i) {
    const bf16* wsa = w_sa_qkv + (size_t)i * 196608;
    const float* sab = dec_sa_qkv_b + (size_t)i * 768;
    const bf16* wca = w_ca_qkv + (size_t)i * 196608;
    const float* cab = dec_ca_qkv_b + (size_t)i * 768;

    // self-attention
    add_bf16_kernel<<<160, 256, 0, stream>>>(tgt, query_embed, tqkb, 40960);
    g64_head(tqkb, wsa, sab, bufQ, 640, 512, 256, 80);                 // Q + K
    g64_head(tgtb, wsa + 131072, sab + 512, bufV, 640, 256, 256, 80);  // V
    attn_mfma<0><<<dim3(64, 2), 256, 0, stream>>>(
        bufQ, bufQ + 163840, bufV, nullptr, taob, 80, 80, scale);
    g64_f(taob, w_sa_out + (size_t)i * 65536, dec_sa_out_b + i * 256, tpr,
          640, 256, 256);
    ln_kernel<<<640, 256, 0, stream>>>(tgt, tpr, nullptr, 0, 0, nullptr,
                                       dec_ln1_g + i * 256, dec_ln1_b + i * 256,
                                       tgt, tgtb);
    // cross-attention
    add_bf16_kernel<<<160, 256, 0, stream>>>(tgt, query_embed, tqkb, 40960);
    g64_head(tqkb, wca, cab, bufQ, 640, 256, 256, 80);                    // Q
    g64_head(qkb, wca + 65536, cab + 256, bufK, 8192, 256, 256, 1024);    // K
    g64_head(memb, wca + 131072, cab + 512, bufV, 8192, 256, 256, 1024);  // V
    attn_mfma<1><<<dim3(64, 2), 256, 0, stream>>>(
        bufQ, bufK, bufV, cam_mask, taob, 80, 1024, scale);
    g64_f(taob, w_ca_out + (size_t)i * 65536, dec_ca_out_b + i * 256, tpr,
          640, 256, 256);
    ln_kernel<<<640, 256, 0, stream>>>(tgt, tpr, nullptr, 0, 0, nullptr,
                                       dec_ln2_g + i * 256, dec_ln2_b + i * 256,
                                       tgt, tgtb);
    // feed-forward
    g64_relu(tgtb, w_dec_ff1 + (size_t)i * 524288, dec_ff1_b + i * 2048, tffb,
             640, 2048, 256);
    mfma_gemm<64, 4, 4><<<dim3(10, 4, 4), 256, 0, stream>>>(
        tffb, w_dec_ff2 + (size_t)i * 524288, nullptr, PO, nullptr,
        640, 256, 2048, 0);
    ln_kernel<<<640, 256, 0, stream>>>(tgt, nullptr, PO, 4, 163840,
                                       dec_ff2_b + i * 256,
                                       dec_ln3_g + i * 256, dec_ln3_b + i * 256,
                                       tgt, tgtb);
  }

  // final norm -> fp32 output
  ln_kernel<<<640, 256, 0, stream>>>(tgt, nullptr, nullptr, 0, 0, nullptr,
                                     dec_norm_g, dec_norm_b,
                                     (float*)d_out, nullptr);
}

// Round 5
// 433.515 us; speedup vs baseline: 5.8850x; 1.1346x over previous
//
#include <hip/hip_runtime.h>
#include <hip/hip_bf16.h>
#include <cstdint>
#include <cstddef>

typedef __hip_bfloat16 bf16;
typedef float f4 __attribute__((ext_vector_type(4)));
typedef float f32x4 __attribute__((ext_vector_type(4)));
typedef short s8v __attribute__((ext_vector_type(8)));
typedef unsigned short u16x4 __attribute__((ext_vector_type(4)));

#define LN_EPS 1e-5f

// async global->LDS 16B per lane: lds dest = base + lane*16 (wave-uniform base)
__device__ __forceinline__ void async_cp16(const void* g, void* lds) {
  __builtin_amdgcn_global_load_lds(
      (const __attribute__((address_space(1))) unsigned int*)g,
      (__attribute__((address_space(3))) unsigned int*)lds, 16, 0, 0);
}

// ------------------------------------------------------------------
// fused multi-segment cast fp32 -> bf16
// ------------------------------------------------------------------
#define NCAST 11
struct CastArgs {
  const float* in[NCAST];
  bf16* out[NCAST];
  int end4[NCAST];
  int nseg;
};

__global__ __launch_bounds__(256) void cast_multi(CastArgs a, int total4) {
  int i = blockIdx.x * 256 + threadIdx.x;
  if (i >= total4) return;
  int s = 0;
  while (i >= a.end4[s]) ++s;
  int j = i - (s ? a.end4[s - 1] : 0);
  f4 v = ((const f4*)a.in[s])[j];
  u16x4 o;
#pragma unroll
  for (int c = 0; c < 4; ++c) {
    bf16 h = __float2bfloat16(v[c]);
    o[c] = *reinterpret_cast<unsigned short*>(&h);
  }
  ((u16x4*)a.out[s])[j] = o;
}

// ------------------------------------------------------------------
// add fp32 + fp32 -> bf16
// ------------------------------------------------------------------
__global__ __launch_bounds__(256) void add_bf16_kernel(const float* __restrict__ a,
                                                       const float* __restrict__ b,
                                                       bf16* __restrict__ out, int n4) {
  int i = blockIdx.x * 256 + threadIdx.x;
  if (i < n4) {
    f4 x = ((const f4*)a)[i];
    f4 y = ((const f4*)b)[i];
    u16x4 o;
#pragma unroll
    for (int j = 0; j < 4; ++j) {
      bf16 h = __float2bfloat16(x[j] + y[j]);
      o[j] = *reinterpret_cast<unsigned short*>(&h);
    }
    ((u16x4*)out)[i] = o;
  }
}

// ------------------------------------------------------------------
// MFMA GEMM: C[M,N] = A[M,K] @ W[N,K]^T (+ bias[N])
// global_load_lds staging, linear LDS [TB][64] bf16, XOR-swizzled source
// columns + swizzled ds_read (involution: slot ^= row&7).
// MODE: 0 f32, 2 bf16+relu, 3 bf16 head layout, 4 f32 split-K partial
// ------------------------------------------------------------------
template <int TB, int MODE, int SPLITK>
__global__ __launch_bounds__(256, 2) void mfma_gemm(
    const bf16* __restrict__ A, const bf16* __restrict__ W,
    const float* __restrict__ bias, float* __restrict__ C,
    bf16* __restrict__ Cb, int M, int N, int K, int HL) {
  constexpr int WM = TB / 2, WN = TB / 2;
  constexpr int MR = WM / 16, NR = WN / 16;
  constexpr int NCH = TB / 32;  // 1KB wave-chunks per matrix per wave
  __shared__ __attribute__((aligned(16))) unsigned short As[TB][64];
  __shared__ __attribute__((aligned(16))) unsigned short Ws[TB][64];
  const int tid = threadIdx.x;
  const int lane = tid & 63, wave = tid >> 6;
  const int wr = wave >> 1, wc = wave & 1;
  const int bm = blockIdx.x * TB, bn = blockIdx.y * TB;
  const int fr = lane & 15, fo = lane >> 4;
  const int srowi = lane >> 3;          // 0..7 within 8-row chunk
  const int slot = lane & 7;
  const int gcol = (slot ^ srowi) * 8;  // pre-swizzled source column (elems)

  const int kchunk = K / SPLITK;
  const int kbeg = (SPLITK > 1) ? blockIdx.z * kchunk : 0;

  f32x4 acc[MR][NR] = {};

  for (int k0 = kbeg; k0 < kbeg + kchunk; k0 += 64) {
    __syncthreads();
#pragma unroll
    for (int c = 0; c < NCH; ++c) {
      int rbase = wave * (TB / 4) + c * 8;
      int row = rbase + srowi;
      async_cp16(A + (size_t)(bm + row) * K + k0 + gcol, &As[rbase][0]);
      async_cp16(W + (size_t)(bn + row) * K + k0 + gcol, &Ws[rbase][0]);
    }
    __syncthreads();
#pragma unroll
    for (int ks = 0; ks < 2; ++ks) {
      s8v a[MR], b[NR];
#pragma unroll
      for (int mi = 0; mi < MR; ++mi) {
        int row = wr * WM + mi * 16 + fr;
        a[mi] = *(const s8v*)((const char*)&As[0][0] + row * 128 +
                              ((ks * 64 + fo * 16) ^ ((row & 7) << 4)));
      }
#pragma unroll
      for (int ni = 0; ni < NR; ++ni) {
        int row = wc * WN + ni * 16 + fr;
        b[ni] = *(const s8v*)((const char*)&Ws[0][0] + row * 128 +
                              ((ks * 64 + fo * 16) ^ ((row & 7) << 4)));
      }
#pragma unroll
      for (int mi = 0; mi < MR; ++mi)
#pragma unroll
        for (int ni = 0; ni < NR; ++ni)
          acc[mi][ni] = __builtin_amdgcn_mfma_f32_16x16x32_bf16(
              a[mi], b[ni], acc[mi][ni], 0, 0, 0);
    }
  }

  const int r0 = (lane >> 4) * 4;
  float* Cz = (MODE == 4) ? C + (size_t)blockIdx.z * M * N : C;
#pragma unroll
  for (int mi = 0; mi < MR; ++mi) {
#pragma unroll
    for (int ni = 0; ni < NR; ++ni) {
      int col = bn + wc * WN + ni * 16 + fr;
      float bv = (MODE == 4) ? 0.f : bias[col];
#pragma unroll
      for (int r = 0; r < 4; ++r) {
        int row = bm + wr * WM + mi * 16 + r0 + r;
        float t = acc[mi][ni][r] + bv;
        if (MODE == 2) t = fmaxf(t, 0.f);
        if (MODE == 0) {
          C[(size_t)row * N + col] = t;
        } else if (MODE == 4) {
          Cz[(size_t)row * N + col] = t;
        } else if (MODE == 3) {
          int l = row >> 3, bb = row & 7;
          int sec = col >> 8, hh = (col >> 5) & 7, d = col & 31;
          Cb[(size_t)sec * ((size_t)64 * HL * 32) +
             ((size_t)(bb * 8 + hh) * HL + l) * 32 + d] = __float2bfloat16(t);
        } else {
          Cb[(size_t)row * N + col] = __float2bfloat16(t);
        }
      }
    }
  }
}

// ------------------------------------------------------------------
// MFMA flash attention with async (T14) K/V staging.
// Q,K,V bf16 head layout (64, L|S, 32). O bf16 (L*8, 256).
// grid (ceil(L/64), 64, NSplit) — consecutive blocks share bh for L2.
// PARTIAL: each z-chunk covers SC keys; writes unscaled O + m + l.
// ------------------------------------------------------------------
template <int HAS_BIAS, int PARTIAL>
__global__ __launch_bounds__(256) void attn_mfma(
    const bf16* __restrict__ Qh, const bf16* __restrict__ Kh,
    const bf16* __restrict__ Vh, const float* __restrict__ bias,
    bf16* __restrict__ O, float* __restrict__ PO, float* __restrict__ PM,
    float* __restrict__ PL, int L, int S, int SC, float scale) {
  __shared__ __attribute__((aligned(16))) unsigned short Ks[64][40];
  __shared__ __attribute__((aligned(16))) unsigned short Vt[32][88];
  __shared__ __attribute__((aligned(16))) unsigned short Ps[4][16][72];
  const int tid = threadIdx.x;
  const int lane = tid & 63, wave = tid >> 6;
  const int fr = lane & 15, fo = lane >> 4;
  const int bh = blockIdx.y;
  const int b = bh >> 3, h = bh & 7;
  const int q0 = blockIdx.x * 64 + wave * 16;

  const int cz = PARTIAL ? blockIdx.z : 0;
  const int sb = PARTIAL ? cz * SC : 0;
  const int se = PARTIAL ? min(S, sb + SC) : S;

  s8v qf = {};
  if (q0 + fr < L)
    qf = *(const s8v*)(Qh + ((size_t)bh * L + q0 + fr) * 32 + fo * 8);

  float m[4] = {-1e30f, -1e30f, -1e30f, -1e30f};
  float lsum[4] = {};
  f32x4 oacc[2] = {};

  const int srow = tid & 63, sco = (tid >> 6) * 8;
  const int qrow_base = q0 + fo * 4;

  // async-stage registers
  s8v kvN = {}, vvN = {};
  auto load_tile = [&](int s0) {
    s8v kv = {}, vv = {};
    if (s0 + srow < se) {
      size_t so = ((size_t)bh * S + s0 + srow) * 32 + sco;
      kv = *(const s8v*)(Kh + so);
      vv = *(const s8v*)(Vh + so);
    }
    kvN = kv; vvN = vv;
  };
  auto store_tile = [&]() {
    *(s8v*)&Ks[srow][sco] = kvN;
#pragma unroll
    for (int j = 0; j < 8; ++j)
      Vt[sco + j][srow] = ((unsigned short*)&vvN)[j];
  };

  // prologue: stage first tile
  load_tile(sb);
  store_tile();
  __syncthreads();

  for (int s0 = sb; s0 < se; s0 += 64) {
    const bool more = (s0 + 64 < se);
    if (more) load_tile(s0 + 64);  // issue early; lands under compute

    // QK^T: 4 blocks of 16 keys
    f32x4 sa[4];
#pragma unroll
    for (int kb = 0; kb < 4; ++kb) {
      s8v bf = *(const s8v*)&Ks[kb * 16 + fr][fo * 8];
      f32x4 z = {};
      sa[kb] = __builtin_amdgcn_mfma_f32_16x16x32_bf16(qf, bf, z, 0, 0, 0);
    }

    float lg[4][4];
#pragma unroll
    for (int kb = 0; kb < 4; ++kb) {
      int key = s0 + kb * 16 + fr;
      bool kok = key < se;
#pragma unroll
      for (int r = 0; r < 4; ++r) {
        float t = sa[kb][r] * scale;
        if (HAS_BIAS) {
          int q = qrow_base + r;
          int qc = q < L ? q : L - 1;
          t += bias[((size_t)b * L + qc) * S + key];
        }
        lg[kb][r] = kok ? t : -1e30f;
      }
    }

    float tm[4];
#pragma unroll
    for (int r = 0; r < 4; ++r)
      tm[r] = fmaxf(fmaxf(lg[0][r], lg[1][r]), fmaxf(lg[2][r], lg[3][r]));
#pragma unroll
    for (int off = 1; off <= 8; off <<= 1)
#pragma unroll
      for (int r = 0; r < 4; ++r)
        tm[r] = fmaxf(tm[r], __shfl_xor(tm[r], off, 64));

    float pr[4][4];
#pragma unroll
    for (int r = 0; r < 4; ++r) {
      float nm = fmaxf(m[r], tm[r]);
      float rs = __expf(m[r] - nm);
      m[r] = nm;
      lsum[r] *= rs;
      oacc[0][r] *= rs;
      oacc[1][r] *= rs;
      float ps = 0.f;
#pragma unroll
      for (int kb = 0; kb < 4; ++kb) {
        float p = __expf(lg[kb][r] - nm);
        pr[kb][r] = p;
        ps += p;
      }
      lsum[r] += ps;
    }

#pragma unroll
    for (int kb = 0; kb < 4; ++kb)
#pragma unroll
      for (int r = 0; r < 4; ++r) {
        bf16 hp = __float2bfloat16(pr[kb][r]);
        Ps[wave][fo * 4 + r][kb * 16 + fr] = *(unsigned short*)&hp;
      }

#pragma unroll
    for (int ks = 0; ks < 2; ++ks) {
      s8v af = *(const s8v*)&Ps[wave][fr][ks * 32 + fo * 8];
#pragma unroll
      for (int dh = 0; dh < 2; ++dh) {
        s8v vf = *(const s8v*)&Vt[dh * 16 + fr][ks * 32 + fo * 8];
        oacc[dh] = __builtin_amdgcn_mfma_f32_16x16x32_bf16(af, vf, oacc[dh], 0, 0, 0);
      }
    }

    if (more) {
      __syncthreads();   // everyone done reading current tile
      store_tile();      // write prefetched tile
      __syncthreads();   // staged
    }
  }

#pragma unroll
  for (int off = 1; off <= 8; off <<= 1)
#pragma unroll
    for (int r = 0; r < 4; ++r)
      lsum[r] += __shfl_xor(lsum[r], off, 64);

#pragma unroll
  for (int r = 0; r < 4; ++r) {
    int q = qrow_base + r;
    if (q < L) {
      if (PARTIAL) {
        size_t pi = ((size_t)cz * 64 + bh) * L + q;
        float* po = PO + pi * 32;
        po[fr] = oacc[0][r];
        po[16 + fr] = oacc[1][r];
        if (fr == 0) { PM[pi] = m[r]; PL[pi] = lsum[r]; }
      } else {
        float inv = 1.f / lsum[r];
        bf16* op = O + ((size_t)q * 8 + b) * 256 + h * 32;
        op[fr] = __float2bfloat16(oacc[0][r] * inv);
        op[16 + fr] = __float2bfloat16(oacc[1][r] * inv);
      }
    }
  }
}

// ------------------------------------------------------------------
// combine NC S-chunk partials -> O bf16 (thread per (bh,q,d))
// ------------------------------------------------------------------
__global__ __launch_bounds__(256) void attn_combine(
    const float* __restrict__ PO, const float* __restrict__ PM,
    const float* __restrict__ PL, bf16* __restrict__ O, int L, int NC) {
  int gid = blockIdx.x * 256 + threadIdx.x;
  if (gid >= 64 * L * 32) return;
  int d = gid & 31;
  int rem = gid >> 5;
  int q = rem % L, bh = rem / L;
  int b = bh >> 3, h = bh & 7;
  float M = -1e30f;
  for (int c = 0; c < NC; ++c) M = fmaxf(M, PM[((size_t)c * 64 + bh) * L + q]);
  float lsum = 0.f, o = 0.f;
  for (int c = 0; c < NC; ++c) {
    size_t pi = ((size_t)c * 64 + bh) * L + q;
    float w = __expf(PM[pi] - M);
    lsum += PL[pi] * w;
    o += PO[pi * 32 + d] * w;
  }
  O[((size_t)q * 8 + b) * 256 + h * 32 + d] = __float2bfloat16(o / lsum);
}

// ------------------------------------------------------------------
// LayerNorm over last dim (256): v = x (+res) (+Σ parts) (+gbias);
// out = LN(v)*g + b ; dual output (f32 + bf16)
// ------------------------------------------------------------------
__global__ __launch_bounds__(256) void ln_kernel(
    const float* __restrict__ x, const float* __restrict__ res,
    const float* __restrict__ parts, int nparts, int pstride,
    const float* __restrict__ gbias,
    const float* __restrict__ g, const float* __restrict__ b,
    float* __restrict__ out, bf16* __restrict__ outb) {
  const int row = blockIdx.x, tid = threadIdx.x;
  size_t idx = (size_t)row * 256 + tid;
  float v = x[idx];
  if (res) v += res[idx];
  if (parts) {
    for (int z = 0; z < nparts; ++z) v += parts[(size_t)z * pstride + idx];
  }
  if (gbias) v += gbias[tid];
  float s = v, s2 = v * v;
#pragma unroll
  for (int off = 32; off >= 1; off >>= 1) {
    s += __shfl_down(s, off);
    s2 += __shfl_down(s2, off);
  }
  __shared__ float red[8];
  int wv = tid >> 6;
  if ((tid & 63) == 0) { red[wv] = s; red[4 + wv] = s2; }
  __syncthreads();
  if (tid == 0) {
    float ts = red[0] + red[1] + red[2] + red[3];
    float ts2 = red[4] + red[5] + red[6] + red[7];
    float mu = ts * (1.f / 256.f);
    float var = ts2 * (1.f / 256.f) - mu * mu;
    red[0] = mu;
    red[1] = rsqrtf(var + LN_EPS);
  }
  __syncthreads();
  float y = (v - red[0]) * red[1] * g[tid] + b[tid];
  if (out) out[idx] = y;
  if (outb) outb[idx] = __float2bfloat16(y);
}

// ------------------------------------------------------------------
// Host orchestration
// ------------------------------------------------------------------
extern "C" void kernel_launch(void* const* d_in, const int* in_sizes, int n_in,
                              void* d_out, int out_size, void* d_ws, size_t ws_size,
                              hipStream_t stream) {
  const float* src         = (const float*)d_in[0];
  const float* pos         = (const float*)d_in[1];
  const float* query_embed = (const float*)d_in[2];
  const float* cam_mask    = (const float*)d_in[3];
  const float* enc_qkv_w   = (const float*)d_in[4];
  const float* enc_qkv_b   = (const float*)d_in[5];
  const float* enc_out_w   = (const float*)d_in[6];
  const float* enc_out_b   = (const float*)d_in[7];
  const float* enc_ln1_g   = (const float*)d_in[8];
  const float* enc_ln1_b   = (const float*)d_in[9];
  const float* enc_ff1_w   = (const float*)d_in[10];
  const float* enc_ff1_b   = (const float*)d_in[11];
  const float* enc_ff2_w   = (const float*)d_in[12];
  const float* enc_ff2_b   = (const float*)d_in[13];
  const float* enc_ln2_g   = (const float*)d_in[14];
  const float* enc_ln2_b   = (const float*)d_in[15];
  const float* dec_sa_qkv_w= (const float*)d_in[16];
  const float* dec_sa_qkv_b= (const float*)d_in[17];
  const float* dec_sa_out_w= (const float*)d_in[18];
  const float* dec_sa_out_b= (const float*)d_in[19];
  const float* dec_ln1_g   = (const float*)d_in[20];
  const float* dec_ln1_b   = (const float*)d_in[21];
  const float* dec_ca_qkv_w= (const float*)d_in[22];
  const float* dec_ca_qkv_b= (const float*)d_in[23];
  const float* dec_ca_out_w= (const float*)d_in[24];
  const float* dec_ca_out_b= (const float*)d_in[25];
  const float* dec_ln2_g   = (const float*)d_in[26];
  const float* dec_ln2_b   = (const float*)d_in[27];
  const float* dec_ff1_w   = (const float*)d_in[28];
  const float* dec_ff1_b   = (const float*)d_in[29];
  const float* dec_ff2_w   = (const float*)d_in[30];
  const float* dec_ff2_b   = (const float*)d_in[31];
  const float* dec_ln3_g   = (const float*)d_in[32];
  const float* dec_ln3_b   = (const float*)d_in[33];
  const float* dec_norm_g  = (const float*)d_in[34];
  const float* dec_norm_b  = (const float*)d_in[35];

  // ---------------- workspace layout ----------------
  size_t off = 0;
  char* base = (char*)d_ws;
  auto af = [&](size_t n) { float* p = (float*)(base + off); off += n * 4; return p; };
  auto ab = [&](size_t n) { bf16*  p = (bf16*)(base + off);  off += n * 2; return p; };

  float* mem  = af(2097152);
  float* r1   = af(2097152);
  float* PO   = af(8388608);   // split-K partials / CA attn partials
  float* pm   = af(262144);
  float* pl   = af(262144);
  float* tgt  = af(163840);
  float* tpr  = af(163840);
  bf16* memb  = ab(2097152);
  bf16* qkb   = ab(2097152);
  bf16* aob   = ab(2097152);
  bf16* ffb   = ab(16777216);
  bf16* bufQ  = ab(4194304);   // Q section + batched-K section
  bf16* bufK  = ab(2097152);
  bf16* bufV  = ab(2097152);
  bf16* tgtb  = ab(163840);
  bf16* tqkb  = ab(163840);
  bf16* taob  = ab(163840);
  bf16* tffb  = ab(1310720);
  bf16* w_enc_qkv = ab(393216);
  bf16* w_enc_out = ab(131072);
  bf16* w_enc_ff1 = ab(1048576);
  bf16* w_enc_ff2 = ab(1048576);
  bf16* w_sa_qkv  = ab(393216);
  bf16* w_sa_out  = ab(131072);
  bf16* w_ca_qkv  = ab(393216);
  bf16* w_ca_out  = ab(131072);
  bf16* w_dec_ff1 = ab(1048576);
  bf16* w_dec_ff2 = ab(1048576);

  const float scale = 0.17677669529663687f;  // 1/sqrt(32)

  // ---- fused weight + src casts ----
  {
    CastArgs ca;
    const float* ins[NCAST] = {enc_qkv_w, enc_out_w, enc_ff1_w, enc_ff2_w,
                               dec_sa_qkv_w, dec_sa_out_w, dec_ca_qkv_w,
                               dec_ca_out_w, dec_ff1_w, dec_ff2_w, src};
    bf16* outs[NCAST] = {w_enc_qkv, w_enc_out, w_enc_ff1, w_enc_ff2,
                         w_sa_qkv, w_sa_out, w_ca_qkv,
                         w_ca_out, w_dec_ff1, w_dec_ff2, memb};
    int n4s[NCAST] = {98304, 32768, 262144, 262144, 98304, 32768, 98304,
                      32768, 262144, 262144, 524288};
    int acc = 0;
    for (int s = 0; s < NCAST; ++s) {
      ca.in[s] = ins[s]; ca.out[s] = outs[s];
      acc += n4s[s]; ca.end4[s] = acc;
    }
    ca.nseg = NCAST;
    cast_multi<<<(acc + 255) / 256, 256, 0, stream>>>(ca, acc);
  }
  hipMemcpyAsync(mem, src, (size_t)2097152 * 4, hipMemcpyDeviceToDevice, stream);

  // GEMM launch helpers
  auto g64_f = [&](const bf16* A, const bf16* W, const float* bias, float* C,
                   int M, int N, int K) {
    mfma_gemm<64, 0, 1><<<dim3(M / 64, N / 64), 256, 0, stream>>>(
        A, W, bias, C, nullptr, M, N, K, 0);
  };
  auto g64_head = [&](const bf16* A, const bf16* W, const float* bias, bf16* Cb,
                      int M, int N, int K, int HL) {
    mfma_gemm<64, 3, 1><<<dim3(M / 64, N / 64), 256, 0, stream>>>(
        A, W, bias, nullptr, Cb, M, N, K, HL);
  };
  auto g64_relu = [&](const bf16* A, const bf16* W, const float* bias, bf16* Cb,
                      int M, int N, int K) {
    mfma_gemm<64, 2, 1><<<dim3(M / 64, N / 64), 256, 0, stream>>>(
        A, W, bias, nullptr, Cb, M, N, K, 0);
  };
  auto g128_relu = [&](const bf16* A, const bf16* W, const float* bias, bf16* Cb,
                       int M, int N, int K) {
    mfma_gemm<128, 2, 1><<<dim3(M / 128, N / 128), 256, 0, stream>>>(
        A, W, bias, nullptr, Cb, M, N, K, 0);
  };

  // ---------------- encoder ----------------
  for (int i = 0; i < 2; ++i) {
    const bf16* wq = w_enc_qkv + (size_t)i * 196608;
    const float* qkvb = enc_qkv_b + (size_t)i * 768;
    add_bf16_kernel<<<2048, 256, 0, stream>>>(mem, pos, qkb, 524288);
    g64_head(qkb, wq, qkvb, bufQ, 8192, 512, 256, 1024);                  // Q + K
    g64_head(memb, wq + 131072, qkvb + 512, bufV, 8192, 256, 256, 1024);  // V
    attn_mfma<0, 0><<<dim3(16, 64), 256, 0, stream>>>(
        bufQ, bufQ + 2097152, bufV, nullptr, aob, nullptr, nullptr, nullptr,
        1024, 1024, 0, scale);
    g64_f(aob, w_enc_out + (size_t)i * 65536, enc_out_b + i * 256, r1,
          8192, 256, 256);
    ln_kernel<<<8192, 256, 0, stream>>>(mem, r1, nullptr, 0, 0, nullptr,
                                        enc_ln1_g + i * 256, enc_ln1_b + i * 256,
                                        mem, memb);
    g128_relu(memb, w_enc_ff1 + (size_t)i * 524288, enc_ff1_b + i * 2048, ffb,
              8192, 2048, 256);
    mfma_gemm<128, 4, 4><<<dim3(64, 2, 4), 256, 0, stream>>>(
        ffb, w_enc_ff2 + (size_t)i * 524288, nullptr, PO, nullptr,
        8192, 256, 2048, 0);
    ln_kernel<<<8192, 256, 0, stream>>>(mem, nullptr, PO, 4, 2097152,
                                        enc_ff2_b + i * 256,
                                        enc_ln2_g + i * 256, enc_ln2_b + i * 256,
                                        mem, memb);
  }

  // ---------------- decoder ----------------
  hipMemsetAsync(tgt, 0, (size_t)163840 * 4, stream);
  hipMemsetAsync(tgtb, 0, (size_t)163840 * 2, stream);
  add_bf16_kernel<<<2048, 256, 0, stream>>>(mem, pos, qkb, 524288);  // CA key input

  for (int i = 0; i < 2; ++i) {
    const bf16* wsa = w_sa_qkv + (size_t)i * 196608;
    const float* sab = dec_sa_qkv_b + (size_t)i * 768;
    const bf16* wca = w_ca_qkv + (size_t)i * 196608;
    const float* cab = dec_ca_qkv_b + (size_t)i * 768;

    // self-attention
    add_bf16_kernel<<<160, 256, 0, stream>>>(tgt, query_embed, tqkb, 40960);
    g64_head(tqkb, wsa, sab, bufQ, 640, 512, 256, 80);                 // Q + K
    g64_head(tgtb, wsa + 131072, sab + 512, bufV, 640, 256, 256, 80);  // V
    attn_mfma<0, 0><<<dim3(2, 64), 256, 0, stream>>>(
        bufQ, bufQ + 163840, bufV, nullptr, taob, nullptr, nullptr, nullptr,
        80, 80, 0, scale);
    g64_f(taob, w_sa_out + (size_t)i * 65536, dec_sa_out_b + i * 256, tpr,
          640, 256, 256);
    ln_kernel<<<640, 256, 0, stream>>>(tgt, tpr, nullptr, 0, 0, nullptr,
                                       dec_ln1_g + i * 256, dec_ln1_b + i * 256,
                                       tgt, tgtb);
    // cross-attention (S split into 8 chunks of 128 + combine)
    add_bf16_kernel<<<160, 256, 0, stream>>>(tgt, query_embed, tqkb, 40960);
    g64_head(tqkb, wca, cab, bufQ, 640, 256, 256, 80);                    // Q
    g64_head(qkb, wca + 65536, cab + 256, bufK, 8192, 256, 256, 1024);    // K
    g64_head(memb, wca + 131072, cab + 512, bufV, 8192, 256, 256, 1024);  // V
    attn_mfma<1, 1><<<dim3(2, 64, 8), 256, 0, stream>>>(
        bufQ, bufK, bufV, cam_mask, nullptr, PO, pm, pl,
        80, 1024, 128, scale);
    attn_combine<<<640, 256, 0, stream>>>(PO, pm, pl, taob, 80, 8);
    g64_f(taob, w_ca_out + (size_t)i * 65536, dec_ca_out_b + i * 256, tpr,
          640, 256, 256);
    ln_kernel<<<640, 256, 0, stream>>>(tgt, tpr, nullptr, 0, 0, nullptr,
                                       dec_ln2_g + i * 256, dec_ln2_b + i * 256,
                                       tgt, tgtb);
    // feed-forward
    g64_relu(tgtb, w_dec_ff1 + (size_t)i * 524288, dec_ff1_b + i * 2048, tffb,
             640, 2048, 256);
    mfma_gemm<64, 4, 4><<<dim3(10, 4, 4), 256, 0, stream>>>(
        tffb, w_dec_ff2 + (size_t)i * 524288, nullptr, PO, nullptr,
        640, 256, 2048, 0);
    ln_kernel<<<640, 256, 0, stream>>>(tgt, nullptr, PO, 4, 163840,
                                       dec_ff2_b + i * 256,
                                       dec_ln3_g + i * 256, dec_ln3_b + i * 256,
                                       tgt, tgtb);
  }

  // final norm -> fp32 output
  ln_kernel<<<640, 256, 0, stream>>>(tgt, nullptr, nullptr, 0, 0, nullptr,
                                     dec_norm_g, dec_norm_b,
                                     (float*)d_out, nullptr);
}